// Round 7
// baseline (1390.026 us; speedup 1.0000x reference)
//
#include <hip/hip_runtime.h>
#include <hip/hip_bf16.h>
#include <hip/hip_fp16.h>
#include <math.h>

#define NV 32000
#define NE 50
#define NH 100
#define NB 8
#define NT 512
#define KP 112    // K padded to 7 k-tiles of 16 for outgemm mfma_32x32x16

typedef __attribute__((ext_vector_type(8)))  _Float16 f16x8;
typedef __attribute__((ext_vector_type(4)))  float    f32x4;
typedef __attribute__((ext_vector_type(16))) float    f32x16;

// ---------------------------------------------------------------------------
// Kernel 0a: fc_W f32 [k][v] -> fp16 MFMA-B-frag order (32x32x16), verified R4.
// ---------------------------------------------------------------------------
__global__ __launch_bounds__(256) void convw_kernel(
    const float* __restrict__ W, _Float16* __restrict__ Wp)
{
    int wv = threadIdx.x >> 6, l = threadIdx.x & 63;
    int ct = blockIdx.x * 4 + wv;
    int v  = ct * 32 + (l & 31);
    int kb = (l >> 5) * 8;
    _Float16* dst = Wp + (size_t)ct * 7 * 512 + l * 8;
    for (int kt = 0; kt < 7; kt++) {
        f16x8 tmp;
        #pragma unroll
        for (int j = 0; j < 8; j++) {
            int k = kt * 16 + kb + j;
            tmp[j] = (_Float16)(k < NH ? W[(size_t)k * NV + v] : 0.0f);
        }
        *(f16x8*)(dst + (size_t)kt * 512) = tmp;
    }
}

// ---------------------------------------------------------------------------
// Kernel 0b: gate weights -> fp16 B-frags for mfma_f32_16x16x32_f16 (verified R5).
// frag f=(g*7+n)*4+kt ; lane l: col n*16+(l&15), k=kt*32+(l>>4)*8+j (0 pad).
// ---------------------------------------------------------------------------
__global__ __launch_bounds__(64) void convg_kernel(
    const float* __restrict__ Whr, const float* __restrict__ Whz,
    const float* __restrict__ Whh, _Float16* __restrict__ Wg)
{
    int f = blockIdx.x;                 // 0..83
    int g = f / 28, rem = f % 28, n = rem / 4, kt = rem % 4;
    const float* W = (g == 0) ? Whr : (g == 1) ? Whz : Whh;
    int l   = threadIdx.x;
    int col = n * 16 + (l & 15);
    int k0  = kt * 32 + (l >> 4) * 8;
    f16x8 v;
    #pragma unroll
    for (int j = 0; j < 8; j++) {
        int k = k0 + j;
        v[j] = (_Float16)((k < NH && col < NH) ? W[k * NH + col] : 0.0f);
    }
    *(f16x8*)(Wg + (size_t)f * 512 + l * 8) = v;
}

// ---------------------------------------------------------------------------
// Kernel 1: embed + input projections (unchanged).
// ---------------------------------------------------------------------------
__global__ __launch_bounds__(128) void xproj_kernel(
    const int* __restrict__ inp, const float* __restrict__ emb,
    const float* __restrict__ Wxr, const float* __restrict__ br,
    const float* __restrict__ Wxz, const float* __restrict__ bz,
    const float* __restrict__ Wxh, const float* __restrict__ bh,
    float* __restrict__ Xr, float* __restrict__ Xz, float* __restrict__ Xh)
{
    int n = blockIdx.x;            // n = t*NB + b
    int t = n >> 3, b = n & 7;
    __shared__ float xs[NE];
    int tid = threadIdx.x;
    int idx = inp[b * NT + t];
    if (tid < NE) xs[tid] = emb[idx * NE + tid];
    __syncthreads();
    if (tid < NH) {
        float ar = br[tid], az = bz[tid], ah = bh[tid];
        for (int e = 0; e < NE; e++) {
            float x = xs[e];
            ar += x * Wxr[e * NH + tid];
            az += x * Wxz[e * NH + tid];
            ah += x * Wxh[e * NH + tid];
        }
        Xr[n * NH + tid] = ar;
        Xz[n * NH + tid] = az;
        Xh[n * NH + tid] = ah;
    }
}

// ---------------------------------------------------------------------------
// Kernel 2: SINGLE-WAVE GRU recurrence. One 64-thread block per batch.
// All 3 gates' B-frags live in this wave's registers (84 x f16x8 = 336 VGPR,
// __launch_bounds__(64,1) -> 512 cap). M=1 MFMA row 0 = the batch. h/rh
// redistribution via a 256B in-wave LDS bounce (lgkmcnt only, ZERO s_barrier).
// x-projections enter as the MFMA C-operand init, prefetched 1 step ahead.
// ---------------------------------------------------------------------------
__global__ __launch_bounds__(64, 1) void gru_rec_kernel(
    const _Float16* __restrict__ Wg,
    const float* __restrict__ Xr, const float* __restrict__ Xz,
    const float* __restrict__ Xh, _Float16* __restrict__ Hp)
{
    const int b  = blockIdx.x;
    const int l  = threadIdx.x;
    const int kg = l >> 4;

    __shared__ __align__(16) _Float16 h16[128];
    __shared__ __align__(16) _Float16 rh16[128];
    h16[l]  = (_Float16)0.0f;  h16[l + 64]  = (_Float16)0.0f;
    rh16[l] = (_Float16)0.0f;  rh16[l + 64] = (_Float16)0.0f;
    __syncthreads();

    // all B fragments in registers
    f16x8 WB[3][7][4];
    #pragma unroll
    for (int g = 0; g < 3; g++)
        #pragma unroll
        for (int n = 0; n < 7; n++)
            #pragma unroll
            for (int kt = 0; kt < 4; kt++)
                WB[g][n][kt] = *(const f16x8*)(Wg + (size_t)((g*7 + n)*4 + kt)*512 + l*8);

    float hcol[7], zv[7], xcr[7], xcz[7], xch[7];
    int   cx[7];
    #pragma unroll
    for (int n = 0; n < 7; n++) {
        hcol[n] = 0.f; zv[n] = 0.f; xcr[n] = 0.f; xcz[n] = 0.f; xch[n] = 0.f;
        int c = n * 16 + l;
        cx[n] = c < NH ? c : NH - 1;
    }

    if (l < 16) {
        int base = b * NH;                       // t = 0
        #pragma unroll
        for (int n = 0; n < 7; n++) {
            xcr[n] = Xr[base + cx[n]];
            xcz[n] = Xz[base + cx[n]];
            xch[n] = Xh[base + cx[n]];
        }
    }

    for (int t = 0; t < NT; t++) {
        // ---- phase 1: R,Z = sigmoid(h @ W + x) ----
        f16x8 Ah[4];
        #pragma unroll
        for (int kt = 0; kt < 4; kt++)
            Ah[kt] = *(const f16x8*)&h16[kg * 8 + kt * 32];

        f32x4 aR[7], aZ[7];
        #pragma unroll
        for (int n = 0; n < 7; n++) {
            aR[n] = (f32x4){xcr[n], 0.f, 0.f, 0.f};
            aZ[n] = (f32x4){xcz[n], 0.f, 0.f, 0.f};
        }
        // prefetch next-step xr,xz (consumed next iteration; latency hidden)
        if (l < 16 && t + 1 < NT) {
            int base = ((t + 1) * NB + b) * NH;
            #pragma unroll
            for (int n = 0; n < 7; n++) {
                xcr[n] = Xr[base + cx[n]];
                xcz[n] = Xz[base + cx[n]];
            }
        }
        #pragma unroll
        for (int kt = 0; kt < 4; kt++) {
            #pragma unroll
            for (int n = 0; n < 7; n++) {
                aR[n] = __builtin_amdgcn_mfma_f32_16x16x32_f16(Ah[kt], WB[0][n][kt], aR[n], 0, 0, 0);
                aZ[n] = __builtin_amdgcn_mfma_f32_16x16x32_f16(Ah[kt], WB[1][n][kt], aZ[n], 0, 0, 0);
            }
        }
        if (l < 16) {
            #pragma unroll
            for (int n = 0; n < 7; n++) {
                float r = 1.0f / (1.0f + __expf(-aR[n][0]));
                zv[n]   = 1.0f / (1.0f + __expf(-aZ[n][0]));
                rh16[n * 16 + l] = (_Float16)(r * hcol[n]);   // hcol==0 for pad cols
            }
        }

        // ---- phase 2: Htilda = tanh(rh @ Whh + x); h update ----
        f16x8 Ar[4];
        #pragma unroll
        for (int kt = 0; kt < 4; kt++)
            Ar[kt] = *(const f16x8*)&rh16[kg * 8 + kt * 32];

        f32x4 aH[7];
        #pragma unroll
        for (int n = 0; n < 7; n++) aH[n] = (f32x4){xch[n], 0.f, 0.f, 0.f};
        if (l < 16 && t + 1 < NT) {
            int base = ((t + 1) * NB + b) * NH;
            #pragma unroll
            for (int n = 0; n < 7; n++) xch[n] = Xh[base + cx[n]];
        }
        #pragma unroll
        for (int kt = 0; kt < 4; kt++)
            #pragma unroll
            for (int n = 0; n < 7; n++)
                aH[n] = __builtin_amdgcn_mfma_f32_16x16x32_f16(Ar[kt], WB[2][n][kt], aH[n], 0, 0, 0);

        if (l < 16) {
            size_t hb = (size_t)(t * NB + b) * KP;
            #pragma unroll
            for (int n = 0; n < 7; n++) {
                float e  = __expf(2.0f * (aH[n][0]));
                float th = 1.0f - 2.0f / (e + 1.0f);
                float hn = fmaf(zv[n], th - hcol[n], hcol[n]);
                hn = (n * 16 + l < NH) ? hn : 0.0f;           // keep pad cols exactly 0
                hcol[n] = hn;
                h16[n * 16 + l] = (_Float16)hn;
                Hp[hb + n * 16 + l] = (_Float16)hn;
            }
        }
    }
}

// ---------------------------------------------------------------------------
// Kernel 3: out-GEMM via fp16 MFMA (unchanged R4, verified).
// ---------------------------------------------------------------------------
__global__ __launch_bounds__(256) void outgemm_kernel(
    const _Float16* __restrict__ Hp, const _Float16* __restrict__ Wp,
    const float* __restrict__ fcb, float* __restrict__ out)
{
    int tid = threadIdx.x;
    int wv = tid >> 6, l = tid & 63;
    int n0 = blockIdx.x * 32;
    int cb = blockIdx.y * 256 + wv * 64;

    const _Float16* arow = Hp + (size_t)(n0 + (l & 31)) * KP + (l >> 5) * 8;
    f16x8 a[7];
    #pragma unroll
    for (int kt = 0; kt < 7; kt++)
        a[kt] = *(const f16x8*)(arow + kt * 16);

    int ct0 = cb >> 5;
    const _Float16* bp = Wp + (size_t)ct0 * 7 * 512 + l * 8;

    f32x16 acc0 = {0,0,0,0,0,0,0,0,0,0,0,0,0,0,0,0};
    f32x16 acc1 = {0,0,0,0,0,0,0,0,0,0,0,0,0,0,0,0};
    #pragma unroll
    for (int kt = 0; kt < 7; kt++) {
        f16x8 b0 = *(const f16x8*)(bp + (size_t)kt * 512);
        f16x8 b1 = *(const f16x8*)(bp + (size_t)(kt + 7) * 512);
        acc0 = __builtin_amdgcn_mfma_f32_32x32x16_f16(a[kt], b0, acc0, 0, 0, 0);
        acc1 = __builtin_amdgcn_mfma_f32_32x32x16_f16(a[kt], b1, acc1, 0, 0, 0);
    }

    int c0 = cb + (l & 31);
    float bias0 = fcb[c0], bias1 = fcb[c0 + 32];
    #pragma unroll
    for (int p = 0; p < 16; p++) {
        int r = (p & 3) + 8 * (p >> 2) + 4 * (l >> 5);
        int m = n0 + r;
        size_t row = (size_t)(m & 7) * NT + (m >> 3);   // b*512 + t
        out[row * NV + c0]      = acc0[p] + bias0;
        out[row * NV + c0 + 32] = acc1[p] + bias1;
    }
}

// ---------------------------------------------------------------------------
extern "C" void kernel_launch(void* const* d_in, const int* in_sizes, int n_in,
                              void* d_out, int out_size, void* d_ws, size_t ws_size,
                              hipStream_t stream)
{
    const int*   inp = (const int*)  d_in[0];
    const float* emb = (const float*)d_in[1];
    const float* Whr = (const float*)d_in[2];
    const float* Wxr = (const float*)d_in[3];
    const float* br  = (const float*)d_in[4];
    const float* Whz = (const float*)d_in[5];
    const float* Wxz = (const float*)d_in[6];
    const float* bz  = (const float*)d_in[7];
    const float* Whh = (const float*)d_in[8];
    const float* Wxh = (const float*)d_in[9];
    const float* bh  = (const float*)d_in[10];
    const float* fcW = (const float*)d_in[11];
    const float* fcb = (const float*)d_in[12];
    float* out = (float*)d_out;

    float*    Xr = (float*)d_ws;                       // [NT*NB*NH] f32
    float*    Xz = Xr + NT * NB * NH;
    float*    Xh = Xz + NT * NB * NH;
    _Float16* Hp = (_Float16*)(Xh + NT * NB * NH);     // [NT*NB][KP] fp16
    _Float16* Wp = Hp + (size_t)NT * NB * KP;          // [1000*7*512] fp16
    _Float16* Wg = Wp + (size_t)1000 * 7 * 512;        // [84*512] fp16

    convw_kernel<<<NV / 32 / 4, 256, 0, stream>>>(fcW, Wp);
    convg_kernel<<<84, 64, 0, stream>>>(Whr, Whz, Whh, Wg);
    xproj_kernel<<<NT * NB, 128, 0, stream>>>(inp, emb, Wxr, br, Wxz, bz, Wxh, bh,
                                              Xr, Xz, Xh);
    gru_rec_kernel<<<NB, 64, 0, stream>>>(Wg, Xr, Xz, Xh, Hp);
    dim3 ggrid(NT * NB / 32, NV / 256);
    outgemm_kernel<<<ggrid, 256, 0, stream>>>(Hp, Wp, fcb, out);
}

// Round 8
// 666.358 us; speedup vs baseline: 2.0860x; 2.0860x over previous
//
#include <hip/hip_runtime.h>
#include <hip/hip_bf16.h>
#include <hip/hip_fp16.h>
#include <math.h>

#define NV 32000
#define NE 50
#define NH 100
#define NB 8
#define NT 512
#define KP 112    // K padded to 7 k-tiles of 16 for outgemm mfma_32x32x16
#define HS 136    // h16/rh16 LDS row stride in fp16 (272 B: 2-way bank max)

#define NBLK   256            // fused kernel grid
#define NCONS  (NBLK - NB)    // 248 consumer blocks
#define NMT    (NT * NB / 32) // 128 m-tiles
#define NNT    (NV / 256)     // 125 n-tiles
#define NTILE  (NMT * NNT)    // 16000 GEMM tiles

typedef __attribute__((ext_vector_type(8)))  _Float16 f16x8;
typedef __attribute__((ext_vector_type(4)))  float    f32x4;
typedef __attribute__((ext_vector_type(16))) float    f32x16;

// LDS-only barrier, race-free (R3): pre-barrier clobber+lgkmcnt pins LDS writes
// before the rendezvous; post-barrier clobber pins reads after. Global loads/
// stores (vmcnt) stay in flight across it.
__device__ __forceinline__ void bar_lgkm() {
    __builtin_amdgcn_sched_barrier(0);
    asm volatile("s_waitcnt lgkmcnt(0)" ::: "memory");
    __builtin_amdgcn_s_barrier();
    asm volatile("" ::: "memory");
    __builtin_amdgcn_sched_barrier(0);
}

// ---------------------------------------------------------------------------
// Kernel A: zero the producer progress counters (fresh every launch).
// ---------------------------------------------------------------------------
__global__ void init_kernel(int* __restrict__ ctr)
{
    if (threadIdx.x < NB)
        __hip_atomic_store(ctr + threadIdx.x, 0, __ATOMIC_RELAXED,
                           __HIP_MEMORY_SCOPE_AGENT);
}

// ---------------------------------------------------------------------------
// Kernel 0a: fc_W f32 [k][v] -> fp16 MFMA-B-frag order (32x32x16), verified R4.
// ---------------------------------------------------------------------------
__global__ __launch_bounds__(256) void convw_kernel(
    const float* __restrict__ W, _Float16* __restrict__ Wp)
{
    int wv = threadIdx.x >> 6, l = threadIdx.x & 63;
    int ct = blockIdx.x * 4 + wv;
    int v  = ct * 32 + (l & 31);
    int kb = (l >> 5) * 8;
    _Float16* dst = Wp + (size_t)ct * 7 * 512 + l * 8;
    for (int kt = 0; kt < 7; kt++) {
        f16x8 tmp;
        #pragma unroll
        for (int j = 0; j < 8; j++) {
            int k = kt * 16 + kb + j;
            tmp[j] = (_Float16)(k < NH ? W[(size_t)k * NV + v] : 0.0f);
        }
        *(f16x8*)(dst + (size_t)kt * 512) = tmp;
    }
}

// ---------------------------------------------------------------------------
// Kernel 0b: gate weights -> fp16 B-frags for mfma_f32_16x16x32_f16 (R5).
// ---------------------------------------------------------------------------
__global__ __launch_bounds__(64) void convg_kernel(
    const float* __restrict__ Whr, const float* __restrict__ Whz,
    const float* __restrict__ Whh, _Float16* __restrict__ Wg)
{
    int f = blockIdx.x;                 // 0..83
    int g = f / 28, rem = f % 28, n = rem / 4, kt = rem % 4;
    const float* W = (g == 0) ? Whr : (g == 1) ? Whz : Whh;
    int l   = threadIdx.x;
    int col = n * 16 + (l & 15);
    int k0  = kt * 32 + (l >> 4) * 8;
    f16x8 v;
    #pragma unroll
    for (int j = 0; j < 8; j++) {
        int k = k0 + j;
        v[j] = (_Float16)((k < NH && col < NH) ? W[k * NH + col] : 0.0f);
    }
    *(f16x8*)(Wg + (size_t)f * 512 + l * 8) = v;
}

// ---------------------------------------------------------------------------
// Kernel 1: embed + input projections (unchanged).
// ---------------------------------------------------------------------------
__global__ __launch_bounds__(128) void xproj_kernel(
    const int* __restrict__ inp, const float* __restrict__ emb,
    const float* __restrict__ Wxr, const float* __restrict__ br,
    const float* __restrict__ Wxz, const float* __restrict__ bz,
    const float* __restrict__ Wxh, const float* __restrict__ bh,
    float* __restrict__ Xr, float* __restrict__ Xz, float* __restrict__ Xh)
{
    int n = blockIdx.x;            // n = t*NB + b
    int t = n >> 3, b = n & 7;
    __shared__ float xs[NE];
    int tid = threadIdx.x;
    int idx = inp[b * NT + t];
    if (tid < NE) xs[tid] = emb[idx * NE + tid];
    __syncthreads();
    if (tid < NH) {
        float ar = br[tid], az = bz[tid], ah = bh[tid];
        for (int e = 0; e < NE; e++) {
            float x = xs[e];
            ar += x * Wxr[e * NH + tid];
            az += x * Wxz[e * NH + tid];
            ah += x * Wxh[e * NH + tid];
        }
        Xr[n * NH + tid] = ar;
        Xz[n * NH + tid] = az;
        Xh[n * NH + tid] = ah;
    }
}

// ---------------------------------------------------------------------------
// Fused kernel: blocks 0..7 = GRU recurrence producer (verified R5 body);
// blocks 8..255 = persistent out-GEMM consumers chasing the producers via
// agent-scope progress counters. NO consumer acquire fences (R6 post-mortem):
// producer RELEASE writes back its L2 before ctr becomes visible; consumers
// touch each Hp line exactly once, strictly after observing ctr, and tile
// boundaries are 128B-aligned -> no stale line can exist in consumer caches.
// ---------------------------------------------------------------------------
__global__ __launch_bounds__(256) void fused_kernel(
    const _Float16* __restrict__ Wg,
    const float* __restrict__ Xr, const float* __restrict__ Xz,
    const float* __restrict__ Xh, _Float16* __restrict__ Hp,
    const _Float16* __restrict__ Wp, const float* __restrict__ fcb,
    float* __restrict__ out, int* __restrict__ ctr)
{
    __shared__ __align__(16) _Float16 h16[16 * HS];
    __shared__ __align__(16) _Float16 rh16[16 * HS];

    int tid = threadIdx.x;

    if (blockIdx.x < NB) {
        // =================== PRODUCER: GRU recurrence ===================
        __builtin_amdgcn_s_setprio(1);
        int b   = blockIdx.x;
        int w   = tid >> 6, l = tid & 63;
        int lj  = l & 15;

        for (int i = tid; i < 16 * HS; i += 256) { h16[i] = (_Float16)0.0f; rh16[i] = (_Float16)0.0f; }
        __syncthreads();

        int n0 = w, n1 = w + 4;
        bool has1 = (n1 < 7);
        int n1c = has1 ? n1 : n0;

        f16x8 WR0[4], WZ0[4], WH0[4], WR1[4], WZ1[4], WH1[4];
        #pragma unroll
        for (int kt = 0; kt < 4; kt++) {
            WR0[kt] = *(const f16x8*)(Wg + (size_t)(((0*7 + n0)*4 + kt))*512 + l*8);
            WZ0[kt] = *(const f16x8*)(Wg + (size_t)(((1*7 + n0)*4 + kt))*512 + l*8);
            WH0[kt] = *(const f16x8*)(Wg + (size_t)(((2*7 + n0)*4 + kt))*512 + l*8);
            WR1[kt] = *(const f16x8*)(Wg + (size_t)(((0*7 + n1c)*4 + kt))*512 + l*8);
            WZ1[kt] = *(const f16x8*)(Wg + (size_t)(((1*7 + n1c)*4 + kt))*512 + l*8);
            WH1[kt] = *(const f16x8*)(Wg + (size_t)(((2*7 + n1c)*4 + kt))*512 + l*8);
        }

        int j0 = n0 * 16 + lj;
        int j1 = n1c * 16 + lj;
        int j0x = j0 < NH ? j0 : NH - 1;
        int j1x = j1 < NH ? j1 : NH - 1;

        float h0 = 0.0f, h1 = 0.0f;
        float xr0, xz0, xh0, xr1, xz1, xh1;
        if (l < 16) {
            int base = b * NH;
            xr0 = Xr[base + j0x]; xz0 = Xz[base + j0x]; xh0 = Xh[base + j0x];
            xr1 = Xr[base + j1x]; xz1 = Xz[base + j1x]; xh1 = Xh[base + j1x];
        }

        int aoff = lj * HS + (l >> 4) * 8;

        for (int t = 0; t < NT; t++) {
            float pr0, pz0, ph0, pr1, pz1, ph1;
            if (l < 16 && t + 1 < NT) {
                int base = ((t + 1) * NB + b) * NH;
                pr0 = Xr[base + j0x]; pz0 = Xz[base + j0x]; ph0 = Xh[base + j0x];
                pr1 = Xr[base + j1x]; pz1 = Xz[base + j1x]; ph1 = Xh[base + j1x];
            }

            // ---- phase 1: R,Z = sigmoid(h @ W + x) ----
            f32x4 aR0 = {0,0,0,0}, aZ0 = {0,0,0,0}, aR1 = {0,0,0,0}, aZ1 = {0,0,0,0};
            #pragma unroll
            for (int kt = 0; kt < 4; kt++) {
                f16x8 a = *(const f16x8*)&h16[aoff + kt * 32];
                aR0 = __builtin_amdgcn_mfma_f32_16x16x32_f16(a, WR0[kt], aR0, 0, 0, 0);
                aZ0 = __builtin_amdgcn_mfma_f32_16x16x32_f16(a, WZ0[kt], aZ0, 0, 0, 0);
                aR1 = __builtin_amdgcn_mfma_f32_16x16x32_f16(a, WR1[kt], aR1, 0, 0, 0);
                aZ1 = __builtin_amdgcn_mfma_f32_16x16x32_f16(a, WZ1[kt], aZ1, 0, 0, 0);
            }
            float z0 = 0.0f, z1 = 0.0f;
            if (l < 16) {
                float r0 = 1.0f / (1.0f + __expf(-(aR0[0] + xr0)));
                z0       = 1.0f / (1.0f + __expf(-(aZ0[0] + xz0)));
                rh16[j0] = (_Float16)(j0 < NH ? r0 * h0 : 0.0f);
                if (has1) {
                    float r1 = 1.0f / (1.0f + __expf(-(aR1[0] + xr1)));
                    z1       = 1.0f / (1.0f + __expf(-(aZ1[0] + xz1)));
                    rh16[j1] = (_Float16)(j1 < NH ? r1 * h1 : 0.0f);
                }
            }
            bar_lgkm();                         // rh16 visible

            // ---- phase 2: Htilda = tanh(rh @ Whh + x); h update ----
            f32x4 aH0 = {0,0,0,0}, aH1 = {0,0,0,0};
            #pragma unroll
            for (int kt = 0; kt < 4; kt++) {
                f16x8 a = *(const f16x8*)&rh16[aoff + kt * 32];
                aH0 = __builtin_amdgcn_mfma_f32_16x16x32_f16(a, WH0[kt], aH0, 0, 0, 0);
                aH1 = __builtin_amdgcn_mfma_f32_16x16x32_f16(a, WH1[kt], aH1, 0, 0, 0);
            }
            if (l < 16) {
                size_t hpb = (size_t)(t * NB + b) * KP;
                {
                    float e  = __expf(2.0f * (aH0[0] + xh0));
                    float ht = 1.0f - 2.0f / (e + 1.0f);
                    float hn = fmaf(z0, ht - h0, h0);
                    hn = (j0 < NH) ? hn : 0.0f;
                    h0 = hn;
                    h16[j0] = (_Float16)hn;
                    Hp[hpb + j0] = (_Float16)hn;
                }
                if (has1) {
                    float e  = __expf(2.0f * (aH1[0] + xh1));
                    float ht = 1.0f - 2.0f / (e + 1.0f);
                    float hn = fmaf(z1, ht - h1, h1);
                    hn = (j1 < NH) ? hn : 0.0f;
                    h1 = hn;
                    h16[j1] = (_Float16)hn;
                    Hp[hpb + j1] = (_Float16)hn;
                }
            }
            bar_lgkm();                         // h16 visible for next step

            // ---- publish progress every 8 steps ----
            if ((t & 7) == 7) {
                // each wave drains its own Hp stores to its L2, rendezvous,
                // then one agent-scope RELEASE (L2 writeback before visibility).
                asm volatile("s_waitcnt vmcnt(0)" ::: "memory");
                __syncthreads();
                if (tid == 0)
                    __hip_atomic_store(ctr + b, t + 1, __ATOMIC_RELEASE,
                                       __HIP_MEMORY_SCOPE_AGENT);
            }

            xr0 = pr0; xz0 = pz0; xh0 = ph0;
            xr1 = pr1; xz1 = pz1; xh1 = ph1;
        }
    } else {
        // =================== CONSUMERS: out-GEMM chase ===================
        int wv = tid >> 6, l = tid & 63;
        int done_upto = 0;

        for (int tile = (int)blockIdx.x - NB; tile < NTILE; tile += NCONS) {
            int mt  = tile / NNT;
            int ntl = tile - mt * NNT;
            int need = mt * 4 + 4;          // t-steps required for this m-tile

            if (need > done_upto) {
                if (tid == 0) {
                    #pragma unroll 1
                    for (int bi = 0; bi < NB; ++bi)
                        while (__hip_atomic_load(ctr + bi, __ATOMIC_RELAXED,
                                                 __HIP_MEMORY_SCOPE_AGENT) < need)
                            __builtin_amdgcn_s_sleep(8);
                }
                __syncthreads();            // orders Hp loads after the poll
                done_upto = need;
            }

            // ---- verified R4 outgemm tile body ----
            int n0 = mt * 32;
            int cb = ntl * 256 + wv * 64;

            const _Float16* arow = Hp + (size_t)(n0 + (l & 31)) * KP + (l >> 5) * 8;
            f16x8 a[7];
            #pragma unroll
            for (int kt = 0; kt < 7; kt++)
                a[kt] = *(const f16x8*)(arow + kt * 16);

            int ct0 = cb >> 5;
            const _Float16* bp = Wp + (size_t)ct0 * 7 * 512 + l * 8;

            f32x16 acc0 = {0,0,0,0,0,0,0,0,0,0,0,0,0,0,0,0};
            f32x16 acc1 = {0,0,0,0,0,0,0,0,0,0,0,0,0,0,0,0};
            #pragma unroll
            for (int kt = 0; kt < 7; kt++) {
                f16x8 b0 = *(const f16x8*)(bp + (size_t)kt * 512);
                f16x8 b1 = *(const f16x8*)(bp + (size_t)(kt + 7) * 512);
                acc0 = __builtin_amdgcn_mfma_f32_32x32x16_f16(a[kt], b0, acc0, 0, 0, 0);
                acc1 = __builtin_amdgcn_mfma_f32_32x32x16_f16(a[kt], b1, acc1, 0, 0, 0);
            }

            int c0 = cb + (l & 31);
            float bias0 = fcb[c0], bias1 = fcb[c0 + 32];
            #pragma unroll
            for (int p = 0; p < 16; p++) {
                int r = (p & 3) + 8 * (p >> 2) + 4 * (l >> 5);
                int m = n0 + r;
                size_t row = (size_t)(m & 7) * NT + (m >> 3);   // b*512 + t
                out[row * NV + c0]      = acc0[p] + bias0;
                out[row * NV + c0 + 32] = acc1[p] + bias1;
            }
        }
    }
}

// ---------------------------------------------------------------------------
extern "C" void kernel_launch(void* const* d_in, const int* in_sizes, int n_in,
                              void* d_out, int out_size, void* d_ws, size_t ws_size,
                              hipStream_t stream)
{
    const int*   inp = (const int*)  d_in[0];
    const float* emb = (const float*)d_in[1];
    const float* Whr = (const float*)d_in[2];
    const float* Wxr = (const float*)d_in[3];
    const float* br  = (const float*)d_in[4];
    const float* Whz = (const float*)d_in[5];
    const float* Wxz = (const float*)d_in[6];
    const float* bz  = (const float*)d_in[7];
    const float* Whh = (const float*)d_in[8];
    const float* Wxh = (const float*)d_in[9];
    const float* bh  = (const float*)d_in[10];
    const float* fcW = (const float*)d_in[11];
    const float* fcb = (const float*)d_in[12];
    float* out = (float*)d_out;

    float*    Xr = (float*)d_ws;                       // [NT*NB*NH] f32
    float*    Xz = Xr + NT * NB * NH;
    float*    Xh = Xz + NT * NB * NH;
    _Float16* Hp = (_Float16*)(Xh + NT * NB * NH);     // [NT*NB][KP] fp16
    _Float16* Wp = Hp + (size_t)NT * NB * KP;          // [1000*7*512] fp16
    _Float16* Wg = Wp + (size_t)1000 * 7 * 512;        // [84*512] fp16
    int*      ct = (int*)(Wg + (size_t)84 * 512);      // [8] progress counters

    init_kernel<<<1, 64, 0, stream>>>(ct);
    convw_kernel<<<NV / 32 / 4, 256, 0, stream>>>(fcW, Wp);
    convg_kernel<<<84, 64, 0, stream>>>(Whr, Whz, Whh, Wg);
    xproj_kernel<<<NT * NB, 128, 0, stream>>>(inp, emb, Wxr, br, Wxz, bz, Wxh, bh,
                                              Xr, Xz, Xh);
    fused_kernel<<<NBLK, 256, 0, stream>>>(Wg, Xr, Xz, Xh, Hp, Wp, fcb, out, ct);
}

// Round 9
// 652.584 us; speedup vs baseline: 2.1300x; 1.0211x over previous
//
#include <hip/hip_runtime.h>
#include <hip/hip_bf16.h>
#include <hip/hip_fp16.h>
#include <math.h>

#define NV 32000
#define NE 50
#define NH 100
#define NB 8
#define NT 512
#define KP 112    // K padded to 7 k-tiles of 16 for outgemm mfma_32x32x16
#define HS 136    // h16/rh16 LDS row stride in fp16 (272 B: 2-way bank max)

#define NBLK   256            // fused kernel grid
#define NCONS  (NBLK - NB)    // 248 consumer blocks
#define NMT    (NT * NB / 32) // 128 m-tiles
#define NNT    (NV / 256)     // 125 n-tiles
#define NTILE  (NMT * NNT)    // 16000 GEMM tiles

typedef __attribute__((ext_vector_type(8)))  _Float16 f16x8;
typedef __attribute__((ext_vector_type(4)))  float    f32x4;
typedef __attribute__((ext_vector_type(16))) float    f32x16;

// LDS-only barrier, race-free (R3): pre-barrier clobber+lgkmcnt pins LDS writes
// before the rendezvous; post-barrier clobber pins reads after. Global loads/
// stores (vmcnt) stay in flight across it.
__device__ __forceinline__ void bar_lgkm() {
    __builtin_amdgcn_sched_barrier(0);
    asm volatile("s_waitcnt lgkmcnt(0)" ::: "memory");
    __builtin_amdgcn_s_barrier();
    asm volatile("" ::: "memory");
    __builtin_amdgcn_sched_barrier(0);
}

// Device-coherent fp16 store (sc1, write-through past the XCD L2 to LLC).
// Keeps the producer's L2 clean so the publish needs NO buffer_wbl2.
__device__ __forceinline__ void store_hp(_Float16* p, float v) {
    _Float16 h = (_Float16)v;
    unsigned short u = __builtin_bit_cast(unsigned short, h);
    __hip_atomic_store((unsigned short*)p, u, __ATOMIC_RELAXED,
                       __HIP_MEMORY_SCOPE_AGENT);
}

// ---------------------------------------------------------------------------
// Kernel A: zero the producer progress counters (fresh every launch).
// ---------------------------------------------------------------------------
__global__ void init_kernel(int* __restrict__ ctr)
{
    if (threadIdx.x < NB)
        __hip_atomic_store(ctr + threadIdx.x, 0, __ATOMIC_RELAXED,
                           __HIP_MEMORY_SCOPE_AGENT);
}

// ---------------------------------------------------------------------------
// Kernel 0a: fc_W f32 [k][v] -> fp16 MFMA-B-frag order (32x32x16), verified R4.
// ---------------------------------------------------------------------------
__global__ __launch_bounds__(256) void convw_kernel(
    const float* __restrict__ W, _Float16* __restrict__ Wp)
{
    int wv = threadIdx.x >> 6, l = threadIdx.x & 63;
    int ct = blockIdx.x * 4 + wv;
    int v  = ct * 32 + (l & 31);
    int kb = (l >> 5) * 8;
    _Float16* dst = Wp + (size_t)ct * 7 * 512 + l * 8;
    for (int kt = 0; kt < 7; kt++) {
        f16x8 tmp;
        #pragma unroll
        for (int j = 0; j < 8; j++) {
            int k = kt * 16 + kb + j;
            tmp[j] = (_Float16)(k < NH ? W[(size_t)k * NV + v] : 0.0f);
        }
        *(f16x8*)(dst + (size_t)kt * 512) = tmp;
    }
}

// ---------------------------------------------------------------------------
// Kernel 0b: gate weights -> fp16 B-frags for mfma_f32_16x16x32_f16 (R5).
// ---------------------------------------------------------------------------
__global__ __launch_bounds__(64) void convg_kernel(
    const float* __restrict__ Whr, const float* __restrict__ Whz,
    const float* __restrict__ Whh, _Float16* __restrict__ Wg)
{
    int f = blockIdx.x;                 // 0..83
    int g = f / 28, rem = f % 28, n = rem / 4, kt = rem % 4;
    const float* W = (g == 0) ? Whr : (g == 1) ? Whz : Whh;
    int l   = threadIdx.x;
    int col = n * 16 + (l & 15);
    int k0  = kt * 32 + (l >> 4) * 8;
    f16x8 v;
    #pragma unroll
    for (int j = 0; j < 8; j++) {
        int k = k0 + j;
        v[j] = (_Float16)((k < NH && col < NH) ? W[k * NH + col] : 0.0f);
    }
    *(f16x8*)(Wg + (size_t)f * 512 + l * 8) = v;
}

// ---------------------------------------------------------------------------
// Kernel 1: embed + input projections (unchanged).
// ---------------------------------------------------------------------------
__global__ __launch_bounds__(128) void xproj_kernel(
    const int* __restrict__ inp, const float* __restrict__ emb,
    const float* __restrict__ Wxr, const float* __restrict__ br,
    const float* __restrict__ Wxz, const float* __restrict__ bz,
    const float* __restrict__ Wxh, const float* __restrict__ bh,
    float* __restrict__ Xr, float* __restrict__ Xz, float* __restrict__ Xh)
{
    int n = blockIdx.x;            // n = t*NB + b
    int t = n >> 3, b = n & 7;
    __shared__ float xs[NE];
    int tid = threadIdx.x;
    int idx = inp[b * NT + t];
    if (tid < NE) xs[tid] = emb[idx * NE + tid];
    __syncthreads();
    if (tid < NH) {
        float ar = br[tid], az = bz[tid], ah = bh[tid];
        for (int e = 0; e < NE; e++) {
            float x = xs[e];
            ar += x * Wxr[e * NH + tid];
            az += x * Wxz[e * NH + tid];
            ah += x * Wxh[e * NH + tid];
        }
        Xr[n * NH + tid] = ar;
        Xz[n * NH + tid] = az;
        Xh[n * NH + tid] = ah;
    }
}

// ---------------------------------------------------------------------------
// Fused kernel: blocks 0..7 = GRU recurrence producer (verified R5 body);
// blocks 8..255 = persistent out-GEMM consumers chasing the producers.
// Hp is written with sc1 (device-coherent) stores -> producer L2 stays clean
// -> publish is just vmcnt(0) + relaxed flag store (NO buffer_wbl2 on the
// serial critical path; that was R8's 189us gap).
// ---------------------------------------------------------------------------
__global__ __launch_bounds__(256) void fused_kernel(
    const _Float16* __restrict__ Wg,
    const float* __restrict__ Xr, const float* __restrict__ Xz,
    const float* __restrict__ Xh, _Float16* __restrict__ Hp,
    const _Float16* __restrict__ Wp, const float* __restrict__ fcb,
    float* __restrict__ out, int* __restrict__ ctr)
{
    __shared__ __align__(16) _Float16 h16[16 * HS];
    __shared__ __align__(16) _Float16 rh16[16 * HS];

    int tid = threadIdx.x;

    if (blockIdx.x < NB) {
        // =================== PRODUCER: GRU recurrence ===================
        __builtin_amdgcn_s_setprio(1);
        int b   = blockIdx.x;
        int w   = tid >> 6, l = tid & 63;
        int lj  = l & 15;

        for (int i = tid; i < 16 * HS; i += 256) { h16[i] = (_Float16)0.0f; rh16[i] = (_Float16)0.0f; }
        __syncthreads();

        int n0 = w, n1 = w + 4;
        bool has1 = (n1 < 7);
        int n1c = has1 ? n1 : n0;

        f16x8 WR0[4], WZ0[4], WH0[4], WR1[4], WZ1[4], WH1[4];
        #pragma unroll
        for (int kt = 0; kt < 4; kt++) {
            WR0[kt] = *(const f16x8*)(Wg + (size_t)(((0*7 + n0)*4 + kt))*512 + l*8);
            WZ0[kt] = *(const f16x8*)(Wg + (size_t)(((1*7 + n0)*4 + kt))*512 + l*8);
            WH0[kt] = *(const f16x8*)(Wg + (size_t)(((2*7 + n0)*4 + kt))*512 + l*8);
            WR1[kt] = *(const f16x8*)(Wg + (size_t)(((0*7 + n1c)*4 + kt))*512 + l*8);
            WZ1[kt] = *(const f16x8*)(Wg + (size_t)(((1*7 + n1c)*4 + kt))*512 + l*8);
            WH1[kt] = *(const f16x8*)(Wg + (size_t)(((2*7 + n1c)*4 + kt))*512 + l*8);
        }

        int j0 = n0 * 16 + lj;
        int j1 = n1c * 16 + lj;
        int j0x = j0 < NH ? j0 : NH - 1;
        int j1x = j1 < NH ? j1 : NH - 1;

        float h0 = 0.0f, h1 = 0.0f;
        float xr0, xz0, xh0, xr1, xz1, xh1;
        if (l < 16) {
            int base = b * NH;
            xr0 = Xr[base + j0x]; xz0 = Xz[base + j0x]; xh0 = Xh[base + j0x];
            xr1 = Xr[base + j1x]; xz1 = Xz[base + j1x]; xh1 = Xh[base + j1x];
        }

        int aoff = lj * HS + (l >> 4) * 8;

        for (int t = 0; t < NT; t++) {
            float pr0, pz0, ph0, pr1, pz1, ph1;
            if (l < 16 && t + 1 < NT) {
                int base = ((t + 1) * NB + b) * NH;
                pr0 = Xr[base + j0x]; pz0 = Xz[base + j0x]; ph0 = Xh[base + j0x];
                pr1 = Xr[base + j1x]; pz1 = Xz[base + j1x]; ph1 = Xh[base + j1x];
            }

            // ---- phase 1: R,Z = sigmoid(h @ W + x) ----
            f32x4 aR0 = {0,0,0,0}, aZ0 = {0,0,0,0}, aR1 = {0,0,0,0}, aZ1 = {0,0,0,0};
            #pragma unroll
            for (int kt = 0; kt < 4; kt++) {
                f16x8 a = *(const f16x8*)&h16[aoff + kt * 32];
                aR0 = __builtin_amdgcn_mfma_f32_16x16x32_f16(a, WR0[kt], aR0, 0, 0, 0);
                aZ0 = __builtin_amdgcn_mfma_f32_16x16x32_f16(a, WZ0[kt], aZ0, 0, 0, 0);
                aR1 = __builtin_amdgcn_mfma_f32_16x16x32_f16(a, WR1[kt], aR1, 0, 0, 0);
                aZ1 = __builtin_amdgcn_mfma_f32_16x16x32_f16(a, WZ1[kt], aZ1, 0, 0, 0);
            }
            float z0 = 0.0f, z1 = 0.0f;
            if (l < 16) {
                float r0 = 1.0f / (1.0f + __expf(-(aR0[0] + xr0)));
                z0       = 1.0f / (1.0f + __expf(-(aZ0[0] + xz0)));
                rh16[j0] = (_Float16)(j0 < NH ? r0 * h0 : 0.0f);
                if (has1) {
                    float r1 = 1.0f / (1.0f + __expf(-(aR1[0] + xr1)));
                    z1       = 1.0f / (1.0f + __expf(-(aZ1[0] + xz1)));
                    rh16[j1] = (_Float16)(j1 < NH ? r1 * h1 : 0.0f);
                }
            }
            bar_lgkm();                         // rh16 visible

            // ---- phase 2: Htilda = tanh(rh @ Whh + x); h update ----
            f32x4 aH0 = {0,0,0,0}, aH1 = {0,0,0,0};
            #pragma unroll
            for (int kt = 0; kt < 4; kt++) {
                f16x8 a = *(const f16x8*)&rh16[aoff + kt * 32];
                aH0 = __builtin_amdgcn_mfma_f32_16x16x32_f16(a, WH0[kt], aH0, 0, 0, 0);
                aH1 = __builtin_amdgcn_mfma_f32_16x16x32_f16(a, WH1[kt], aH1, 0, 0, 0);
            }
            if (l < 16) {
                size_t hpb = (size_t)(t * NB + b) * KP;
                {
                    float e  = __expf(2.0f * (aH0[0] + xh0));
                    float ht = 1.0f - 2.0f / (e + 1.0f);
                    float hn = fmaf(z0, ht - h0, h0);
                    hn = (j0 < NH) ? hn : 0.0f;
                    h0 = hn;
                    h16[j0] = (_Float16)hn;
                    store_hp(Hp + hpb + j0, hn);
                }
                if (has1) {
                    float e  = __expf(2.0f * (aH1[0] + xh1));
                    float ht = 1.0f - 2.0f / (e + 1.0f);
                    float hn = fmaf(z1, ht - h1, h1);
                    hn = (j1 < NH) ? hn : 0.0f;
                    h1 = hn;
                    h16[j1] = (_Float16)hn;
                    store_hp(Hp + hpb + j1, hn);
                }
            }
            bar_lgkm();                         // h16 visible for next step

            // ---- publish progress every 8 steps ----
            if ((t & 7) == 7) {
                // sc1 Hp stores retire at the LLC; vmcnt(0) drains them, then
                // a relaxed agent flag store (LLC serializes flag-after-data).
                asm volatile("s_waitcnt vmcnt(0)" ::: "memory");
                __syncthreads();
                if (tid == 0)
                    __hip_atomic_store(ctr + b, t + 1, __ATOMIC_RELAXED,
                                       __HIP_MEMORY_SCOPE_AGENT);
            }

            xr0 = pr0; xz0 = pz0; xh0 = ph0;
            xr1 = pr1; xz1 = pz1; xh1 = ph1;
        }
    } else {
        // =================== CONSUMERS: out-GEMM chase ===================
        int wv = tid >> 6, l = tid & 63;
        int done_upto = 0;

        for (int tile = (int)blockIdx.x - NB; tile < NTILE; tile += NCONS) {
            int mt  = tile / NNT;
            int ntl = tile - mt * NNT;
            int need = mt * 4 + 4;          // t-steps required for this m-tile

            if (need > done_upto) {
                if (tid == 0) {
                    #pragma unroll 1
                    for (int bi = 0; bi < NB; ++bi)
                        while (__hip_atomic_load(ctr + bi, __ATOMIC_RELAXED,
                                                 __HIP_MEMORY_SCOPE_AGENT) < need)
                            __builtin_amdgcn_s_sleep(8);
                }
                __syncthreads();            // orders Hp loads after the poll
                done_upto = need;
            }

            // ---- verified R4 outgemm tile body ----
            int n0 = mt * 32;
            int cb = ntl * 256 + wv * 64;

            const _Float16* arow = Hp + (size_t)(n0 + (l & 31)) * KP + (l >> 5) * 8;
            f16x8 a[7];
            #pragma unroll
            for (int kt = 0; kt < 7; kt++)
                a[kt] = *(const f16x8*)(arow + kt * 16);

            int ct0 = cb >> 5;
            const _Float16* bp = Wp + (size_t)ct0 * 7 * 512 + l * 8;

            f32x16 acc0 = {0,0,0,0,0,0,0,0,0,0,0,0,0,0,0,0};
            f32x16 acc1 = {0,0,0,0,0,0,0,0,0,0,0,0,0,0,0,0};
            #pragma unroll
            for (int kt = 0; kt < 7; kt++) {
                f16x8 b0 = *(const f16x8*)(bp + (size_t)kt * 512);
                f16x8 b1 = *(const f16x8*)(bp + (size_t)(kt + 7) * 512);
                acc0 = __builtin_amdgcn_mfma_f32_32x32x16_f16(a[kt], b0, acc0, 0, 0, 0);
                acc1 = __builtin_amdgcn_mfma_f32_32x32x16_f16(a[kt], b1, acc1, 0, 0, 0);
            }

            int c0 = cb + (l & 31);
            float bias0 = fcb[c0], bias1 = fcb[c0 + 32];
            #pragma unroll
            for (int p = 0; p < 16; p++) {
                int r = (p & 3) + 8 * (p >> 2) + 4 * (l >> 5);
                int m = n0 + r;
                size_t row = (size_t)(m & 7) * NT + (m >> 3);   // b*512 + t
                out[row * NV + c0]      = acc0[p] + bias0;
                out[row * NV + c0 + 32] = acc1[p] + bias1;
            }
        }
    }
}

// ---------------------------------------------------------------------------
extern "C" void kernel_launch(void* const* d_in, const int* in_sizes, int n_in,
                              void* d_out, int out_size, void* d_ws, size_t ws_size,
                              hipStream_t stream)
{
    const int*   inp = (const int*)  d_in[0];
    const float* emb = (const float*)d_in[1];
    const float* Whr = (const float*)d_in[2];
    const float* Wxr = (const float*)d_in[3];
    const float* br  = (const float*)d_in[4];
    const float* Whz = (const float*)d_in[5];
    const float* Wxz = (const float*)d_in[6];
    const float* bz  = (const float*)d_in[7];
    const float* Whh = (const float*)d_in[8];
    const float* Wxh = (const float*)d_in[9];
    const float* bh  = (const float*)d_in[10];
    const float* fcW = (const float*)d_in[11];
    const float* fcb = (const float*)d_in[12];
    float* out = (float*)d_out;

    float*    Xr = (float*)d_ws;                       // [NT*NB*NH] f32
    float*    Xz = Xr + NT * NB * NH;
    float*    Xh = Xz + NT * NB * NH;
    _Float16* Hp = (_Float16*)(Xh + NT * NB * NH);     // [NT*NB][KP] fp16
    _Float16* Wp = Hp + (size_t)NT * NB * KP;          // [1000*7*512] fp16
    _Float16* Wg = Wp + (size_t)1000 * 7 * 512;        // [84*512] fp16
    int*      ct = (int*)(Wg + (size_t)84 * 512);      // [8] progress counters

    init_kernel<<<1, 64, 0, stream>>>(ct);
    convw_kernel<<<NV / 32 / 4, 256, 0, stream>>>(fcW, Wp);
    convg_kernel<<<84, 64, 0, stream>>>(Whr, Whz, Whh, Wg);
    xproj_kernel<<<NT * NB, 128, 0, stream>>>(inp, emb, Wxr, br, Wxz, bz, Wxh, bh,
                                              Xr, Xz, Xh);
    fused_kernel<<<NBLK, 256, 0, stream>>>(Wg, Xr, Xz, Xh, Hp, Wp, fcb, out, ct);
}

// Round 10
// 634.101 us; speedup vs baseline: 2.1921x; 1.0291x over previous
//
#include <hip/hip_runtime.h>
#include <hip/hip_bf16.h>
#include <hip/hip_fp16.h>
#include <math.h>

#define NV 32000
#define NE 50
#define NH 100
#define NB 8
#define NT 512
#define KP 112    // K padded to 7 k-tiles of 16 for outgemm mfma_32x32x16
#define HS 136    // h16/rh16 LDS row stride in fp16 (272 B: 2-way bank max)

#define NBLK   256            // fused kernel grid
#define NCONS  (NBLK - NB)    // 248 consumer blocks
#define NMT    (NT * NB / 32) // 128 m-tiles
#define NNT    (NV / 256)     // 125 n-tiles (123 split in half + 2 full = 248)

typedef __attribute__((ext_vector_type(8)))  _Float16 f16x8;
typedef __attribute__((ext_vector_type(4)))  float    f32x4;
typedef __attribute__((ext_vector_type(16))) float    f32x16;

// LDS-only barrier, race-free (R3): pre-barrier clobber+lgkmcnt pins LDS writes
// before the rendezvous; post-barrier clobber pins reads after. Global loads/
// stores (vmcnt) stay in flight across it.
__device__ __forceinline__ void bar_lgkm() {
    __builtin_amdgcn_sched_barrier(0);
    asm volatile("s_waitcnt lgkmcnt(0)" ::: "memory");
    __builtin_amdgcn_s_barrier();
    asm volatile("" ::: "memory");
    __builtin_amdgcn_sched_barrier(0);
}

// Device-coherent fp16 store (sc1, write-through past the XCD L2 to LLC).
// Keeps the producer's L2 clean so the publish needs NO buffer_wbl2.
__device__ __forceinline__ void store_hp(_Float16* p, float v) {
    _Float16 h = (_Float16)v;
    unsigned short u = __builtin_bit_cast(unsigned short, h);
    __hip_atomic_store((unsigned short*)p, u, __ATOMIC_RELAXED,
                       __HIP_MEMORY_SCOPE_AGENT);
}

// ---------------------------------------------------------------------------
// Kernel A: zero the producer progress counters (fresh every launch).
// ---------------------------------------------------------------------------
__global__ void init_kernel(int* __restrict__ ctr)
{
    if (threadIdx.x < NB)
        __hip_atomic_store(ctr + threadIdx.x, 0, __ATOMIC_RELAXED,
                           __HIP_MEMORY_SCOPE_AGENT);
}

// ---------------------------------------------------------------------------
// Kernel 0a: fc_W f32 [k][v] -> fp16 MFMA-B-frag order (32x32x16), verified R4.
// ---------------------------------------------------------------------------
__global__ __launch_bounds__(256) void convw_kernel(
    const float* __restrict__ W, _Float16* __restrict__ Wp)
{
    int wv = threadIdx.x >> 6, l = threadIdx.x & 63;
    int ct = blockIdx.x * 4 + wv;
    int v  = ct * 32 + (l & 31);
    int kb = (l >> 5) * 8;
    _Float16* dst = Wp + (size_t)ct * 7 * 512 + l * 8;
    for (int kt = 0; kt < 7; kt++) {
        f16x8 tmp;
        #pragma unroll
        for (int j = 0; j < 8; j++) {
            int k = kt * 16 + kb + j;
            tmp[j] = (_Float16)(k < NH ? W[(size_t)k * NV + v] : 0.0f);
        }
        *(f16x8*)(dst + (size_t)kt * 512) = tmp;
    }
}

// ---------------------------------------------------------------------------
// Kernel 0b: gate weights -> fp16 B-frags for mfma_f32_16x16x32_f16 (R5).
// ---------------------------------------------------------------------------
__global__ __launch_bounds__(64) void convg_kernel(
    const float* __restrict__ Whr, const float* __restrict__ Whz,
    const float* __restrict__ Whh, _Float16* __restrict__ Wg)
{
    int f = blockIdx.x;                 // 0..83
    int g = f / 28, rem = f % 28, n = rem / 4, kt = rem % 4;
    const float* W = (g == 0) ? Whr : (g == 1) ? Whz : Whh;
    int l   = threadIdx.x;
    int col = n * 16 + (l & 15);
    int k0  = kt * 32 + (l >> 4) * 8;
    f16x8 v;
    #pragma unroll
    for (int j = 0; j < 8; j++) {
        int k = k0 + j;
        v[j] = (_Float16)((k < NH && col < NH) ? W[k * NH + col] : 0.0f);
    }
    *(f16x8*)(Wg + (size_t)f * 512 + l * 8) = v;
}

// ---------------------------------------------------------------------------
// Kernel 1: embed + input projections (unchanged).
// ---------------------------------------------------------------------------
__global__ __launch_bounds__(128) void xproj_kernel(
    const int* __restrict__ inp, const float* __restrict__ emb,
    const float* __restrict__ Wxr, const float* __restrict__ br,
    const float* __restrict__ Wxz, const float* __restrict__ bz,
    const float* __restrict__ Wxh, const float* __restrict__ bh,
    float* __restrict__ Xr, float* __restrict__ Xz, float* __restrict__ Xh)
{
    int n = blockIdx.x;            // n = t*NB + b
    int t = n >> 3, b = n & 7;
    __shared__ float xs[NE];
    int tid = threadIdx.x;
    int idx = inp[b * NT + t];
    if (tid < NE) xs[tid] = emb[idx * NE + tid];
    __syncthreads();
    if (tid < NH) {
        float ar = br[tid], az = bz[tid], ah = bh[tid];
        for (int e = 0; e < NE; e++) {
            float x = xs[e];
            ar += x * Wxr[e * NH + tid];
            az += x * Wxz[e * NH + tid];
            ah += x * Wxh[e * NH + tid];
        }
        Xr[n * NH + tid] = ar;
        Xz[n * NH + tid] = az;
        Xh[n * NH + tid] = ah;
    }
}

// ---------------------------------------------------------------------------
// Fused kernel: blocks 0..7 = GRU recurrence producer (verified R5 body, sc1
// Hp stores, vmcnt-only publish); blocks 8..255 = persistent out-GEMM
// consumers. NEW (R10): each consumer OWNS one n-tile (Wp slab hoisted to
// registers, zero Wp re-reads) and walks m-tiles ascending — kills the 463 MB
// HBM re-fetch that was thrashing L2/LLC and slowing the producers.
// ---------------------------------------------------------------------------
__global__ __launch_bounds__(256) void fused_kernel(
    const _Float16* __restrict__ Wg,
    const float* __restrict__ Xr, const float* __restrict__ Xz,
    const float* __restrict__ Xh, _Float16* __restrict__ Hp,
    const _Float16* __restrict__ Wp, const float* __restrict__ fcb,
    float* __restrict__ out, int* __restrict__ ctr)
{
    __shared__ __align__(16) _Float16 h16[16 * HS];
    __shared__ __align__(16) _Float16 rh16[16 * HS];

    int tid = threadIdx.x;

    if (blockIdx.x < NB) {
        // =================== PRODUCER: GRU recurrence ===================
        __builtin_amdgcn_s_setprio(1);
        int b   = blockIdx.x;
        int w   = tid >> 6, l = tid & 63;
        int lj  = l & 15;

        for (int i = tid; i < 16 * HS; i += 256) { h16[i] = (_Float16)0.0f; rh16[i] = (_Float16)0.0f; }
        __syncthreads();

        int n0 = w, n1 = w + 4;
        bool has1 = (n1 < 7);
        int n1c = has1 ? n1 : n0;

        f16x8 WR0[4], WZ0[4], WH0[4], WR1[4], WZ1[4], WH1[4];
        #pragma unroll
        for (int kt = 0; kt < 4; kt++) {
            WR0[kt] = *(const f16x8*)(Wg + (size_t)(((0*7 + n0)*4 + kt))*512 + l*8);
            WZ0[kt] = *(const f16x8*)(Wg + (size_t)(((1*7 + n0)*4 + kt))*512 + l*8);
            WH0[kt] = *(const f16x8*)(Wg + (size_t)(((2*7 + n0)*4 + kt))*512 + l*8);
            WR1[kt] = *(const f16x8*)(Wg + (size_t)(((0*7 + n1c)*4 + kt))*512 + l*8);
            WZ1[kt] = *(const f16x8*)(Wg + (size_t)(((1*7 + n1c)*4 + kt))*512 + l*8);
            WH1[kt] = *(const f16x8*)(Wg + (size_t)(((2*7 + n1c)*4 + kt))*512 + l*8);
        }

        int j0 = n0 * 16 + lj;
        int j1 = n1c * 16 + lj;
        int j0x = j0 < NH ? j0 : NH - 1;
        int j1x = j1 < NH ? j1 : NH - 1;

        float h0 = 0.0f, h1 = 0.0f;
        float xr0, xz0, xh0, xr1, xz1, xh1;
        if (l < 16) {
            int base = b * NH;
            xr0 = Xr[base + j0x]; xz0 = Xz[base + j0x]; xh0 = Xh[base + j0x];
            xr1 = Xr[base + j1x]; xz1 = Xz[base + j1x]; xh1 = Xh[base + j1x];
        }

        int aoff = lj * HS + (l >> 4) * 8;

        for (int t = 0; t < NT; t++) {
            float pr0, pz0, ph0, pr1, pz1, ph1;
            if (l < 16 && t + 1 < NT) {
                int base = ((t + 1) * NB + b) * NH;
                pr0 = Xr[base + j0x]; pz0 = Xz[base + j0x]; ph0 = Xh[base + j0x];
                pr1 = Xr[base + j1x]; pz1 = Xz[base + j1x]; ph1 = Xh[base + j1x];
            }

            // ---- phase 1: R,Z = sigmoid(h @ W + x) ----
            f32x4 aR0 = {0,0,0,0}, aZ0 = {0,0,0,0}, aR1 = {0,0,0,0}, aZ1 = {0,0,0,0};
            #pragma unroll
            for (int kt = 0; kt < 4; kt++) {
                f16x8 a = *(const f16x8*)&h16[aoff + kt * 32];
                aR0 = __builtin_amdgcn_mfma_f32_16x16x32_f16(a, WR0[kt], aR0, 0, 0, 0);
                aZ0 = __builtin_amdgcn_mfma_f32_16x16x32_f16(a, WZ0[kt], aZ0, 0, 0, 0);
                aR1 = __builtin_amdgcn_mfma_f32_16x16x32_f16(a, WR1[kt], aR1, 0, 0, 0);
                aZ1 = __builtin_amdgcn_mfma_f32_16x16x32_f16(a, WZ1[kt], aZ1, 0, 0, 0);
            }
            float z0 = 0.0f, z1 = 0.0f;
            if (l < 16) {
                float r0 = 1.0f / (1.0f + __expf(-(aR0[0] + xr0)));
                z0       = 1.0f / (1.0f + __expf(-(aZ0[0] + xz0)));
                rh16[j0] = (_Float16)(j0 < NH ? r0 * h0 : 0.0f);
                if (has1) {
                    float r1 = 1.0f / (1.0f + __expf(-(aR1[0] + xr1)));
                    z1       = 1.0f / (1.0f + __expf(-(aZ1[0] + xz1)));
                    rh16[j1] = (_Float16)(j1 < NH ? r1 * h1 : 0.0f);
                }
            }
            bar_lgkm();                         // rh16 visible

            // ---- phase 2: Htilda = tanh(rh @ Whh + x); h update ----
            f32x4 aH0 = {0,0,0,0}, aH1 = {0,0,0,0};
            #pragma unroll
            for (int kt = 0; kt < 4; kt++) {
                f16x8 a = *(const f16x8*)&rh16[aoff + kt * 32];
                aH0 = __builtin_amdgcn_mfma_f32_16x16x32_f16(a, WH0[kt], aH0, 0, 0, 0);
                aH1 = __builtin_amdgcn_mfma_f32_16x16x32_f16(a, WH1[kt], aH1, 0, 0, 0);
            }
            if (l < 16) {
                size_t hpb = (size_t)(t * NB + b) * KP;
                {
                    float e  = __expf(2.0f * (aH0[0] + xh0));
                    float ht = 1.0f - 2.0f / (e + 1.0f);
                    float hn = fmaf(z0, ht - h0, h0);
                    hn = (j0 < NH) ? hn : 0.0f;
                    h0 = hn;
                    h16[j0] = (_Float16)hn;
                    store_hp(Hp + hpb + j0, hn);
                }
                if (has1) {
                    float e  = __expf(2.0f * (aH1[0] + xh1));
                    float ht = 1.0f - 2.0f / (e + 1.0f);
                    float hn = fmaf(z1, ht - h1, h1);
                    hn = (j1 < NH) ? hn : 0.0f;
                    h1 = hn;
                    h16[j1] = (_Float16)hn;
                    store_hp(Hp + hpb + j1, hn);
                }
            }
            bar_lgkm();                         // h16 visible for next step

            // ---- publish progress every 8 steps ----
            if ((t & 7) == 7) {
                // sc1 Hp stores retire at the LLC; vmcnt(0) drains them, then
                // a relaxed agent flag store (LLC serializes flag-after-data).
                asm volatile("s_waitcnt vmcnt(0)" ::: "memory");
                __syncthreads();
                if (tid == 0)
                    __hip_atomic_store(ctr + b, t + 1, __ATOMIC_RELAXED,
                                       __HIP_MEMORY_SCOPE_AGENT);
            }

            xr0 = pr0; xz0 = pz0; xh0 = ph0;
            xr1 = pr1; xz1 = pz1; xh1 = ph1;
        }
    } else {
        // ============ CONSUMERS: out-GEMM, n-tile-resident mapping ============
        // c < 125: own n-tile c; m-range [0,64) (or full [0,128) for ntl 123,124).
        // c >= 125: own n-tile c-125 (0..122); m-range [64,128).
        int c  = (int)blockIdx.x - NB;       // 0..247
        int wv = tid >> 6, l = tid & 63;
        int ntl, mlo, mhi;
        if (c < NNT) { ntl = c;       mlo = 0;       mhi = (ntl < NNT - 2) ? NMT / 2 : NMT; }
        else         { ntl = c - NNT; mlo = NMT / 2; mhi = NMT; }

        int cb  = ntl * 256 + wv * 64;
        int ct0 = cb >> 5;
        const _Float16* bp = Wp + (size_t)ct0 * 7 * 512 + l * 8;
        f16x8 wb0[7], wb1[7];                // Wp slab in registers for life
        #pragma unroll
        for (int kt = 0; kt < 7; kt++) {
            wb0[kt] = *(const f16x8*)(bp + (size_t)kt * 512);
            wb1[kt] = *(const f16x8*)(bp + (size_t)(kt + 7) * 512);
        }
        int c0 = cb + (l & 31);
        float bias0 = fcb[c0], bias1 = fcb[c0 + 32];

        int done_upto = 0;
        for (int mt = mlo; mt < mhi; mt++) {
            int need = mt * 4 + 4;           // t-steps required for this m-tile
            if (need > done_upto) {
                if (tid == 0) {
                    #pragma unroll 1
                    for (int bi = 0; bi < NB; ++bi) {
                        int cur;
                        while ((cur = __hip_atomic_load(ctr + bi, __ATOMIC_RELAXED,
                                                        __HIP_MEMORY_SCOPE_AGENT)) < need) {
                            if (need - cur > 16) __builtin_amdgcn_s_sleep(64);
                            else                 __builtin_amdgcn_s_sleep(8);
                        }
                    }
                }
                __syncthreads();             // orders Hp loads after the poll
                done_upto = need;
            }

            int n0 = mt * 32;
            const _Float16* arow = Hp + (size_t)(n0 + (l & 31)) * KP + (l >> 5) * 8;
            f16x8 a[7];
            #pragma unroll
            for (int kt = 0; kt < 7; kt++)
                a[kt] = *(const f16x8*)(arow + kt * 16);

            f32x16 acc0 = {0,0,0,0,0,0,0,0,0,0,0,0,0,0,0,0};
            f32x16 acc1 = {0,0,0,0,0,0,0,0,0,0,0,0,0,0,0,0};
            #pragma unroll
            for (int kt = 0; kt < 7; kt++) {
                acc0 = __builtin_amdgcn_mfma_f32_32x32x16_f16(a[kt], wb0[kt], acc0, 0, 0, 0);
                acc1 = __builtin_amdgcn_mfma_f32_32x32x16_f16(a[kt], wb1[kt], acc1, 0, 0, 0);
            }

            #pragma unroll
            for (int p = 0; p < 16; p++) {
                int r = (p & 3) + 8 * (p >> 2) + 4 * (l >> 5);
                int m = n0 + r;
                size_t row = (size_t)(m & 7) * NT + (m >> 3);   // b*512 + t
                out[row * NV + c0]      = acc0[p] + bias0;
                out[row * NV + c0 + 32] = acc1[p] + bias1;
            }
        }
    }
}

// ---------------------------------------------------------------------------
extern "C" void kernel_launch(void* const* d_in, const int* in_sizes, int n_in,
                              void* d_out, int out_size, void* d_ws, size_t ws_size,
                              hipStream_t stream)
{
    const int*   inp = (const int*)  d_in[0];
    const float* emb = (const float*)d_in[1];
    const float* Whr = (const float*)d_in[2];
    const float* Wxr = (const float*)d_in[3];
    const float* br  = (const float*)d_in[4];
    const float* Whz = (const float*)d_in[5];
    const float* Wxz = (const float*)d_in[6];
    const float* bz  = (const float*)d_in[7];
    const float* Whh = (const float*)d_in[8];
    const float* Wxh = (const float*)d_in[9];
    const float* bh  = (const float*)d_in[10];
    const float* fcW = (const float*)d_in[11];
    const float* fcb = (const float*)d_in[12];
    float* out = (float*)d_out;

    float*    Xr = (float*)d_ws;                       // [NT*NB*NH] f32
    float*    Xz = Xr + NT * NB * NH;
    float*    Xh = Xz + NT * NB * NH;
    _Float16* Hp = (_Float16*)(Xh + NT * NB * NH);     // [NT*NB][KP] fp16
    _Float16* Wp = Hp + (size_t)NT * NB * KP;          // [1000*7*512] fp16
    _Float16* Wg = Wp + (size_t)1000 * 7 * 512;        // [84*512] fp16
    int*      ct = (int*)(Wg + (size_t)84 * 512);      // [8] progress counters

    init_kernel<<<1, 64, 0, stream>>>(ct);
    convw_kernel<<<NV / 32 / 4, 256, 0, stream>>>(fcW, Wp);
    convg_kernel<<<84, 64, 0, stream>>>(Whr, Whz, Whh, Wg);
    xproj_kernel<<<NT * NB, 128, 0, stream>>>(inp, emb, Wxr, br, Wxz, bz, Wxh, bh,
                                              Xr, Xz, Xh);
    fused_kernel<<<NBLK, 256, 0, stream>>>(Wg, Xr, Xz, Xh, Hp, Wp, fcb, out, ct);
}

// Round 11
// 624.278 us; speedup vs baseline: 2.2266x; 1.0157x over previous
//
#include <hip/hip_runtime.h>
#include <hip/hip_bf16.h>
#include <hip/hip_fp16.h>
#include <math.h>

#define NV 32000
#define NE 50
#define NH 100
#define NB 8
#define NT 512
#define KP 112    // K padded to 7 k-tiles of 16 for outgemm mfma_32x32x16
#define HS 136    // h16/rh16 LDS row stride in fp16 (272 B: 2-way bank max)

#define NBLK   256            // fused kernel grid = CU count
#define NCONS  (NBLK - NB)    // 248 consumer blocks
#define NMT    (NT * NB / 32) // 128 m-tiles
#define NNT    (NV / 256)     // 125 n-tiles (123 split in half + 2 full = 248)

typedef __attribute__((ext_vector_type(8)))  _Float16 f16x8;
typedef __attribute__((ext_vector_type(4)))  float    f32x4;
typedef __attribute__((ext_vector_type(16))) float    f32x16;

// LDS-only barrier, race-free (R3): pre-barrier clobber+lgkmcnt pins LDS writes
// before the rendezvous; post-barrier clobber pins reads after. Global loads/
// stores (vmcnt) stay in flight across it.
__device__ __forceinline__ void bar_lgkm() {
    __builtin_amdgcn_sched_barrier(0);
    asm volatile("s_waitcnt lgkmcnt(0)" ::: "memory");
    __builtin_amdgcn_s_barrier();
    asm volatile("" ::: "memory");
    __builtin_amdgcn_sched_barrier(0);
}

// Device-coherent fp16 store (sc1, write-through past the XCD L2 to LLC).
// Keeps the producer's L2 clean so the publish needs NO buffer_wbl2.
__device__ __forceinline__ void store_hp(_Float16* p, float v) {
    _Float16 h = (_Float16)v;
    unsigned short u = __builtin_bit_cast(unsigned short, h);
    __hip_atomic_store((unsigned short*)p, u, __ATOMIC_RELAXED,
                       __HIP_MEMORY_SCOPE_AGENT);
}

// ---------------------------------------------------------------------------
// Kernel A: zero the producer progress counters (fresh every launch).
// ---------------------------------------------------------------------------
__global__ void init_kernel(int* __restrict__ ctr)
{
    if (threadIdx.x < NB)
        __hip_atomic_store(ctr + threadIdx.x, 0, __ATOMIC_RELAXED,
                           __HIP_MEMORY_SCOPE_AGENT);
}

// ---------------------------------------------------------------------------
// Kernel 0a: fc_W f32 [k][v] -> fp16 MFMA-B-frag order (32x32x16), verified R4.
// ---------------------------------------------------------------------------
__global__ __launch_bounds__(256) void convw_kernel(
    const float* __restrict__ W, _Float16* __restrict__ Wp)
{
    int wv = threadIdx.x >> 6, l = threadIdx.x & 63;
    int ct = blockIdx.x * 4 + wv;
    int v  = ct * 32 + (l & 31);
    int kb = (l >> 5) * 8;
    _Float16* dst = Wp + (size_t)ct * 7 * 512 + l * 8;
    for (int kt = 0; kt < 7; kt++) {
        f16x8 tmp;
        #pragma unroll
        for (int j = 0; j < 8; j++) {
            int k = kt * 16 + kb + j;
            tmp[j] = (_Float16)(k < NH ? W[(size_t)k * NV + v] : 0.0f);
        }
        *(f16x8*)(dst + (size_t)kt * 512) = tmp;
    }
}

// ---------------------------------------------------------------------------
// Kernel 0b: gate weights -> fp16 B-frags for mfma_f32_16x16x32_f16 (R5).
// ---------------------------------------------------------------------------
__global__ __launch_bounds__(64) void convg_kernel(
    const float* __restrict__ Whr, const float* __restrict__ Whz,
    const float* __restrict__ Whh, _Float16* __restrict__ Wg)
{
    int f = blockIdx.x;                 // 0..83
    int g = f / 28, rem = f % 28, n = rem / 4, kt = rem % 4;
    const float* W = (g == 0) ? Whr : (g == 1) ? Whz : Whh;
    int l   = threadIdx.x;
    int col = n * 16 + (l & 15);
    int k0  = kt * 32 + (l >> 4) * 8;
    f16x8 v;
    #pragma unroll
    for (int j = 0; j < 8; j++) {
        int k = k0 + j;
        v[j] = (_Float16)((k < NH && col < NH) ? W[k * NH + col] : 0.0f);
    }
    *(f16x8*)(Wg + (size_t)f * 512 + l * 8) = v;
}

// ---------------------------------------------------------------------------
// Kernel 1: embed + input projections (unchanged).
// ---------------------------------------------------------------------------
__global__ __launch_bounds__(128) void xproj_kernel(
    const int* __restrict__ inp, const float* __restrict__ emb,
    const float* __restrict__ Wxr, const float* __restrict__ br,
    const float* __restrict__ Wxz, const float* __restrict__ bz,
    const float* __restrict__ Wxh, const float* __restrict__ bh,
    float* __restrict__ Xr, float* __restrict__ Xz, float* __restrict__ Xh)
{
    int n = blockIdx.x;            // n = t*NB + b
    int t = n >> 3, b = n & 7;
    __shared__ float xs[NE];
    int tid = threadIdx.x;
    int idx = inp[b * NT + t];
    if (tid < NE) xs[tid] = emb[idx * NE + tid];
    __syncthreads();
    if (tid < NH) {
        float ar = br[tid], az = bz[tid], ah = bh[tid];
        for (int e = 0; e < NE; e++) {
            float x = xs[e];
            ar += x * Wxr[e * NH + tid];
            az += x * Wxz[e * NH + tid];
            ah += x * Wxh[e * NH + tid];
        }
        Xr[n * NH + tid] = ar;
        Xz[n * NH + tid] = az;
        Xh[n * NH + tid] = ah;
    }
}

// ---------------------------------------------------------------------------
// Fused kernel: blocks 0..7 = GRU recurrence producer (verified R5 body, sc1
// Hp stores, vmcnt-only publish); blocks 8..255 = n-tile-resident out-GEMM
// consumers (Wp slab in registers). NEW (R11): 96 KB static LDS forces
// EXACTLY ONE BLOCK PER CU (>160/2 KB), so no consumer block can co-reside
// on a producer CU and pollute its serial critical path.
// ---------------------------------------------------------------------------
__global__ __launch_bounds__(256) void fused_kernel(
    const _Float16* __restrict__ Wg,
    const float* __restrict__ Xr, const float* __restrict__ Xz,
    const float* __restrict__ Xh, _Float16* __restrict__ Hp,
    const _Float16* __restrict__ Wp, const float* __restrict__ fcb,
    float* __restrict__ out, int* __restrict__ ctr)
{
    // 96 KB static LDS: occupancy limiter (1 block/CU). Producers use the
    // first 2*16*HS halves as h16/rh16; the rest is deliberate padding.
    __shared__ __align__(16) _Float16 big_lds[49152];
    _Float16* h16  = big_lds;
    _Float16* rh16 = big_lds + 16 * HS;

    int tid = threadIdx.x;

    if (blockIdx.x < NB) {
        // =================== PRODUCER: GRU recurrence ===================
        __builtin_amdgcn_s_setprio(1);
        int b   = blockIdx.x;
        int w   = tid >> 6, l = tid & 63;
        int lj  = l & 15;

        for (int i = tid; i < 16 * HS; i += 256) { h16[i] = (_Float16)0.0f; rh16[i] = (_Float16)0.0f; }
        __syncthreads();

        int n0 = w, n1 = w + 4;
        bool has1 = (n1 < 7);
        int n1c = has1 ? n1 : n0;

        f16x8 WR0[4], WZ0[4], WH0[4], WR1[4], WZ1[4], WH1[4];
        #pragma unroll
        for (int kt = 0; kt < 4; kt++) {
            WR0[kt] = *(const f16x8*)(Wg + (size_t)(((0*7 + n0)*4 + kt))*512 + l*8);
            WZ0[kt] = *(const f16x8*)(Wg + (size_t)(((1*7 + n0)*4 + kt))*512 + l*8);
            WH0[kt] = *(const f16x8*)(Wg + (size_t)(((2*7 + n0)*4 + kt))*512 + l*8);
            WR1[kt] = *(const f16x8*)(Wg + (size_t)(((0*7 + n1c)*4 + kt))*512 + l*8);
            WZ1[kt] = *(const f16x8*)(Wg + (size_t)(((1*7 + n1c)*4 + kt))*512 + l*8);
            WH1[kt] = *(const f16x8*)(Wg + (size_t)(((2*7 + n1c)*4 + kt))*512 + l*8);
        }

        int j0 = n0 * 16 + lj;
        int j1 = n1c * 16 + lj;
        int j0x = j0 < NH ? j0 : NH - 1;
        int j1x = j1 < NH ? j1 : NH - 1;

        float h0 = 0.0f, h1 = 0.0f;
        float xr0, xz0, xh0, xr1, xz1, xh1;
        if (l < 16) {
            int base = b * NH;
            xr0 = Xr[base + j0x]; xz0 = Xz[base + j0x]; xh0 = Xh[base + j0x];
            xr1 = Xr[base + j1x]; xz1 = Xz[base + j1x]; xh1 = Xh[base + j1x];
        }

        int aoff = lj * HS + (l >> 4) * 8;

        for (int t = 0; t < NT; t++) {
            float pr0, pz0, ph0, pr1, pz1, ph1;
            if (l < 16 && t + 1 < NT) {
                int base = ((t + 1) * NB + b) * NH;
                pr0 = Xr[base + j0x]; pz0 = Xz[base + j0x]; ph0 = Xh[base + j0x];
                pr1 = Xr[base + j1x]; pz1 = Xz[base + j1x]; ph1 = Xh[base + j1x];
            }

            // ---- phase 1: R,Z = sigmoid(h @ W + x) ----
            f32x4 aR0 = {0,0,0,0}, aZ0 = {0,0,0,0}, aR1 = {0,0,0,0}, aZ1 = {0,0,0,0};
            #pragma unroll
            for (int kt = 0; kt < 4; kt++) {
                f16x8 a = *(const f16x8*)&h16[aoff + kt * 32];
                aR0 = __builtin_amdgcn_mfma_f32_16x16x32_f16(a, WR0[kt], aR0, 0, 0, 0);
                aZ0 = __builtin_amdgcn_mfma_f32_16x16x32_f16(a, WZ0[kt], aZ0, 0, 0, 0);
                aR1 = __builtin_amdgcn_mfma_f32_16x16x32_f16(a, WR1[kt], aR1, 0, 0, 0);
                aZ1 = __builtin_amdgcn_mfma_f32_16x16x32_f16(a, WZ1[kt], aZ1, 0, 0, 0);
            }
            float z0 = 0.0f, z1 = 0.0f;
            if (l < 16) {
                float r0 = 1.0f / (1.0f + __expf(-(aR0[0] + xr0)));
                z0       = 1.0f / (1.0f + __expf(-(aZ0[0] + xz0)));
                rh16[j0] = (_Float16)(j0 < NH ? r0 * h0 : 0.0f);
                if (has1) {
                    float r1 = 1.0f / (1.0f + __expf(-(aR1[0] + xr1)));
                    z1       = 1.0f / (1.0f + __expf(-(aZ1[0] + xz1)));
                    rh16[j1] = (_Float16)(j1 < NH ? r1 * h1 : 0.0f);
                }
            }
            bar_lgkm();                         // rh16 visible

            // ---- phase 2: Htilda = tanh(rh @ Whh + x); h update ----
            f32x4 aH0 = {0,0,0,0}, aH1 = {0,0,0,0};
            #pragma unroll
            for (int kt = 0; kt < 4; kt++) {
                f16x8 a = *(const f16x8*)&rh16[aoff + kt * 32];
                aH0 = __builtin_amdgcn_mfma_f32_16x16x32_f16(a, WH0[kt], aH0, 0, 0, 0);
                aH1 = __builtin_amdgcn_mfma_f32_16x16x32_f16(a, WH1[kt], aH1, 0, 0, 0);
            }
            if (l < 16) {
                size_t hpb = (size_t)(t * NB + b) * KP;
                {
                    float e  = __expf(2.0f * (aH0[0] + xh0));
                    float ht = 1.0f - 2.0f / (e + 1.0f);
                    float hn = fmaf(z0, ht - h0, h0);
                    hn = (j0 < NH) ? hn : 0.0f;
                    h0 = hn;
                    h16[j0] = (_Float16)hn;
                    store_hp(Hp + hpb + j0, hn);
                }
                if (has1) {
                    float e  = __expf(2.0f * (aH1[0] + xh1));
                    float ht = 1.0f - 2.0f / (e + 1.0f);
                    float hn = fmaf(z1, ht - h1, h1);
                    hn = (j1 < NH) ? hn : 0.0f;
                    h1 = hn;
                    h16[j1] = (_Float16)hn;
                    store_hp(Hp + hpb + j1, hn);
                }
            }
            bar_lgkm();                         // h16 visible for next step

            // ---- publish progress every 8 steps ----
            if ((t & 7) == 7) {
                // sc1 Hp stores retire at the LLC; vmcnt(0) drains them, then
                // a relaxed agent flag store (LLC serializes flag-after-data).
                asm volatile("s_waitcnt vmcnt(0)" ::: "memory");
                __syncthreads();
                if (tid == 0)
                    __hip_atomic_store(ctr + b, t + 1, __ATOMIC_RELAXED,
                                       __HIP_MEMORY_SCOPE_AGENT);
            }

            xr0 = pr0; xz0 = pz0; xh0 = ph0;
            xr1 = pr1; xz1 = pz1; xh1 = ph1;
        }
    } else {
        // ============ CONSUMERS: out-GEMM, n-tile-resident mapping ============
        int c  = (int)blockIdx.x - NB;       // 0..247
        int wv = tid >> 6, l = tid & 63;
        int ntl, mlo, mhi;
        if (c < NNT) { ntl = c;       mlo = 0;       mhi = (ntl < NNT - 2) ? NMT / 2 : NMT; }
        else         { ntl = c - NNT; mlo = NMT / 2; mhi = NMT; }

        int cb  = ntl * 256 + wv * 64;
        int ct0 = cb >> 5;
        const _Float16* bp = Wp + (size_t)ct0 * 7 * 512 + l * 8;
        f16x8 wb0[7], wb1[7];                // Wp slab in registers for life
        #pragma unroll
        for (int kt = 0; kt < 7; kt++) {
            wb0[kt] = *(const f16x8*)(bp + (size_t)kt * 512);
            wb1[kt] = *(const f16x8*)(bp + (size_t)(kt + 7) * 512);
        }
        int c0 = cb + (l & 31);
        float bias0 = fcb[c0], bias1 = fcb[c0 + 32];

        int done_upto = 0;
        for (int mt = mlo; mt < mhi; mt++) {
            int need = mt * 4 + 4;           // t-steps required for this m-tile
            if (need > done_upto) {
                if (tid == 0) {
                    #pragma unroll 1
                    for (int bi = 0; bi < NB; ++bi) {
                        int cur;
                        while ((cur = __hip_atomic_load(ctr + bi, __ATOMIC_RELAXED,
                                                        __HIP_MEMORY_SCOPE_AGENT)) < need) {
                            if (need - cur > 16) __builtin_amdgcn_s_sleep(64);
                            else                 __builtin_amdgcn_s_sleep(8);
                        }
                    }
                }
                __syncthreads();             // orders Hp loads after the poll
                done_upto = need;
            }

            int n0 = mt * 32;
            const _Float16* arow = Hp + (size_t)(n0 + (l & 31)) * KP + (l >> 5) * 8;
            f16x8 a[7];
            #pragma unroll
            for (int kt = 0; kt < 7; kt++)
                a[kt] = *(const f16x8*)(arow + kt * 16);

            f32x16 acc0 = {0,0,0,0,0,0,0,0,0,0,0,0,0,0,0,0};
            f32x16 acc1 = {0,0,0,0,0,0,0,0,0,0,0,0,0,0,0,0};
            #pragma unroll
            for (int kt = 0; kt < 7; kt++) {
                acc0 = __builtin_amdgcn_mfma_f32_32x32x16_f16(a[kt], wb0[kt], acc0, 0, 0, 0);
                acc1 = __builtin_amdgcn_mfma_f32_32x32x16_f16(a[kt], wb1[kt], acc1, 0, 0, 0);
            }

            #pragma unroll
            for (int p = 0; p < 16; p++) {
                int r = (p & 3) + 8 * (p >> 2) + 4 * (l >> 5);
                int m = n0 + r;
                size_t row = (size_t)(m & 7) * NT + (m >> 3);   // b*512 + t
                out[row * NV + c0]      = acc0[p] + bias0;
                out[row * NV + c0 + 32] = acc1[p] + bias1;
            }
        }
    }
}

// ---------------------------------------------------------------------------
extern "C" void kernel_launch(void* const* d_in, const int* in_sizes, int n_in,
                              void* d_out, int out_size, void* d_ws, size_t ws_size,
                              hipStream_t stream)
{
    const int*   inp = (const int*)  d_in[0];
    const float* emb = (const float*)d_in[1];
    const float* Whr = (const float*)d_in[2];
    const float* Wxr = (const float*)d_in[3];
    const float* br  = (const float*)d_in[4];
    const float* Whz = (const float*)d_in[5];
    const float* Wxz = (const float*)d_in[6];
    const float* bz  = (const float*)d_in[7];
    const float* Whh = (const float*)d_in[8];
    const float* Wxh = (const float*)d_in[9];
    const float* bh  = (const float*)d_in[10];
    const float* fcW = (const float*)d_in[11];
    const float* fcb = (const float*)d_in[12];
    float* out = (float*)d_out;

    float*    Xr = (float*)d_ws;                       // [NT*NB*NH] f32
    float*    Xz = Xr + NT * NB * NH;
    float*    Xh = Xz + NT * NB * NH;
    _Float16* Hp = (_Float16*)(Xh + NT * NB * NH);     // [NT*NB][KP] fp16
    _Float16* Wp = Hp + (size_t)NT * NB * KP;          // [1000*7*512] fp16
    _Float16* Wg = Wp + (size_t)1000 * 7 * 512;        // [84*512] fp16
    int*      ct = (int*)(Wg + (size_t)84 * 512);      // [8] progress counters

    init_kernel<<<1, 64, 0, stream>>>(ct);
    convw_kernel<<<NV / 32 / 4, 256, 0, stream>>>(fcW, Wp);
    convg_kernel<<<84, 64, 0, stream>>>(Whr, Whz, Whh, Wg);
    xproj_kernel<<<NT * NB, 128, 0, stream>>>(inp, emb, Wxr, br, Wxz, bz, Wxh, bh,
                                              Xr, Xz, Xh);
    fused_kernel<<<NBLK, 256, 0, stream>>>(Wg, Xr, Xz, Xh, Hp, Wp, fcb, out, ct);
}

// Round 12
// 624.032 us; speedup vs baseline: 2.2275x; 1.0004x over previous
//
#include <hip/hip_runtime.h>
#include <hip/hip_bf16.h>
#include <hip/hip_fp16.h>
#include <math.h>

#define NV 32000
#define NE 50
#define NH 100
#define NB 8
#define NT 512
#define KP 112    // K padded to 7 k-tiles of 16 for outgemm mfma_32x32x16
#define HS 136    // h16/rh16 LDS row stride in fp16 (272 B: 2-way bank max)

#define NBLK   256            // fused kernel grid = CU count
#define NCONS  (NBLK - NB)    // 248 consumer blocks
#define NMT    (NT * NB / 32) // 128 m-tiles
#define NNT    (NV / 256)     // 125 n-tiles (123 split in half + 2 full = 248)

typedef __attribute__((ext_vector_type(8)))  _Float16 f16x8;
typedef __attribute__((ext_vector_type(4)))  float    f32x4;
typedef __attribute__((ext_vector_type(16))) float    f32x16;

// LDS-only barrier, race-free (R3): pre-barrier clobber+lgkmcnt pins LDS writes
// before the rendezvous; post-barrier clobber pins reads after. Global loads/
// stores (vmcnt) stay in flight across it.
__device__ __forceinline__ void bar_lgkm() {
    __builtin_amdgcn_sched_barrier(0);
    asm volatile("s_waitcnt lgkmcnt(0)" ::: "memory");
    __builtin_amdgcn_s_barrier();
    asm volatile("" ::: "memory");
    __builtin_amdgcn_sched_barrier(0);
}

// Device-coherent fp16 store (sc1, write-through past the XCD L2 to LLC).
// Keeps the producer's L2 clean so the publish needs NO buffer_wbl2.
__device__ __forceinline__ void store_hp(_Float16* p, float v) {
    _Float16 h = (_Float16)v;
    unsigned short u = __builtin_bit_cast(unsigned short, h);
    __hip_atomic_store((unsigned short*)p, u, __ATOMIC_RELAXED,
                       __HIP_MEMORY_SCOPE_AGENT);
}

// ---------------------------------------------------------------------------
// Kernel A: zero the producer progress counters (fresh every launch).
// ---------------------------------------------------------------------------
__global__ void init_kernel(int* __restrict__ ctr)
{
    if (threadIdx.x < NB)
        __hip_atomic_store(ctr + threadIdx.x, 0, __ATOMIC_RELAXED,
                           __HIP_MEMORY_SCOPE_AGENT);
}

// ---------------------------------------------------------------------------
// Kernel 0a: fc_W f32 [k][v] -> fp16 MFMA-B-frag order (32x32x16), verified R4.
// ---------------------------------------------------------------------------
__global__ __launch_bounds__(256) void convw_kernel(
    const float* __restrict__ W, _Float16* __restrict__ Wp)
{
    int wv = threadIdx.x >> 6, l = threadIdx.x & 63;
    int ct = blockIdx.x * 4 + wv;
    int v  = ct * 32 + (l & 31);
    int kb = (l >> 5) * 8;
    _Float16* dst = Wp + (size_t)ct * 7 * 512 + l * 8;
    for (int kt = 0; kt < 7; kt++) {
        f16x8 tmp;
        #pragma unroll
        for (int j = 0; j < 8; j++) {
            int k = kt * 16 + kb + j;
            tmp[j] = (_Float16)(k < NH ? W[(size_t)k * NV + v] : 0.0f);
        }
        *(f16x8*)(dst + (size_t)kt * 512) = tmp;
    }
}

// ---------------------------------------------------------------------------
// Kernel 0b: gate weights -> fp16 B-frags for mfma_f32_16x16x32_f16 (R5).
// ---------------------------------------------------------------------------
__global__ __launch_bounds__(64) void convg_kernel(
    const float* __restrict__ Whr, const float* __restrict__ Whz,
    const float* __restrict__ Whh, _Float16* __restrict__ Wg)
{
    int f = blockIdx.x;                 // 0..83
    int g = f / 28, rem = f % 28, n = rem / 4, kt = rem % 4;
    const float* W = (g == 0) ? Whr : (g == 1) ? Whz : Whh;
    int l   = threadIdx.x;
    int col = n * 16 + (l & 15);
    int k0  = kt * 32 + (l >> 4) * 8;
    f16x8 v;
    #pragma unroll
    for (int j = 0; j < 8; j++) {
        int k = k0 + j;
        v[j] = (_Float16)((k < NH && col < NH) ? W[k * NH + col] : 0.0f);
    }
    *(f16x8*)(Wg + (size_t)f * 512 + l * 8) = v;
}

// ---------------------------------------------------------------------------
// Kernel 1: embed + input projections (unchanged).
// ---------------------------------------------------------------------------
__global__ __launch_bounds__(128) void xproj_kernel(
    const int* __restrict__ inp, const float* __restrict__ emb,
    const float* __restrict__ Wxr, const float* __restrict__ br,
    const float* __restrict__ Wxz, const float* __restrict__ bz,
    const float* __restrict__ Wxh, const float* __restrict__ bh,
    float* __restrict__ Xr, float* __restrict__ Xz, float* __restrict__ Xh)
{
    int n = blockIdx.x;            // n = t*NB + b
    int t = n >> 3, b = n & 7;
    __shared__ float xs[NE];
    int tid = threadIdx.x;
    int idx = inp[b * NT + t];
    if (tid < NE) xs[tid] = emb[idx * NE + tid];
    __syncthreads();
    if (tid < NH) {
        float ar = br[tid], az = bz[tid], ah = bh[tid];
        for (int e = 0; e < NE; e++) {
            float x = xs[e];
            ar += x * Wxr[e * NH + tid];
            az += x * Wxz[e * NH + tid];
            ah += x * Wxh[e * NH + tid];
        }
        Xr[n * NH + tid] = ar;
        Xz[n * NH + tid] = az;
        Xh[n * NH + tid] = ah;
    }
}

// ---------------------------------------------------------------------------
// Fused kernel. R12 change: __launch_bounds__(256, 1). The 96 KB LDS already
// pins 1 block/CU (4 waves on 4 SIMDs = 1 wave/EU), so raising the VGPR cap
// is free — and it lets the compiler ACTUALLY keep the producer's 24 weight
// fragments (96 VGPR) in registers. R3/R5/R11's VGPR_Count (52/76/132) proves
// they were silently demoted and re-read from L2 every step: 98-160 KB/step
// at ~135 GB/s per-CU L2 BW = the measured ~0.9 us/step floor of BOTH the
// VALU and MFMA recurrence variants.
// ---------------------------------------------------------------------------
__global__ __launch_bounds__(256, 1) void fused_kernel(
    const _Float16* __restrict__ Wg,
    const float* __restrict__ Xr, const float* __restrict__ Xz,
    const float* __restrict__ Xh, _Float16* __restrict__ Hp,
    const _Float16* __restrict__ Wp, const float* __restrict__ fcb,
    float* __restrict__ out, int* __restrict__ ctr)
{
    // 96 KB static LDS: occupancy limiter (1 block/CU). Producers use the
    // first 2*16*HS halves as h16/rh16; the rest is deliberate padding.
    __shared__ __align__(16) _Float16 big_lds[49152];
    _Float16* h16  = big_lds;
    _Float16* rh16 = big_lds + 16 * HS;

    int tid = threadIdx.x;

    if (blockIdx.x < NB) {
        // =================== PRODUCER: GRU recurrence ===================
        __builtin_amdgcn_s_setprio(1);
        int b   = blockIdx.x;
        int w   = tid >> 6, l = tid & 63;
        int lj  = l & 15;

        for (int i = tid; i < 16 * HS; i += 256) { h16[i] = (_Float16)0.0f; rh16[i] = (_Float16)0.0f; }
        __syncthreads();

        int n0 = w, n1 = w + 4;
        bool has1 = (n1 < 7);
        int n1c = has1 ? n1 : n0;

        f16x8 WR0[4], WZ0[4], WH0[4], WR1[4], WZ1[4], WH1[4];
        #pragma unroll
        for (int kt = 0; kt < 4; kt++) {
            WR0[kt] = *(const f16x8*)(Wg + (size_t)(((0*7 + n0)*4 + kt))*512 + l*8);
            WZ0[kt] = *(const f16x8*)(Wg + (size_t)(((1*7 + n0)*4 + kt))*512 + l*8);
            WH0[kt] = *(const f16x8*)(Wg + (size_t)(((2*7 + n0)*4 + kt))*512 + l*8);
            WR1[kt] = *(const f16x8*)(Wg + (size_t)(((0*7 + n1c)*4 + kt))*512 + l*8);
            WZ1[kt] = *(const f16x8*)(Wg + (size_t)(((1*7 + n1c)*4 + kt))*512 + l*8);
            WH1[kt] = *(const f16x8*)(Wg + (size_t)(((2*7 + n1c)*4 + kt))*512 + l*8);
        }

        int j0 = n0 * 16 + lj;
        int j1 = n1c * 16 + lj;
        int j0x = j0 < NH ? j0 : NH - 1;
        int j1x = j1 < NH ? j1 : NH - 1;

        float h0 = 0.0f, h1 = 0.0f;
        float xr0, xz0, xh0, xr1, xz1, xh1;
        if (l < 16) {
            int base = b * NH;
            xr0 = Xr[base + j0x]; xz0 = Xz[base + j0x]; xh0 = Xh[base + j0x];
            xr1 = Xr[base + j1x]; xz1 = Xz[base + j1x]; xh1 = Xh[base + j1x];
        }

        int aoff = lj * HS + (l >> 4) * 8;

        for (int t = 0; t < NT; t++) {
            float pr0, pz0, ph0, pr1, pz1, ph1;
            if (l < 16 && t + 1 < NT) {
                int base = ((t + 1) * NB + b) * NH;
                pr0 = Xr[base + j0x]; pz0 = Xz[base + j0x]; ph0 = Xh[base + j0x];
                pr1 = Xr[base + j1x]; pz1 = Xz[base + j1x]; ph1 = Xh[base + j1x];
            }

            // ---- phase 1: R,Z = sigmoid(h @ W + x) ----
            f32x4 aR0 = {0,0,0,0}, aZ0 = {0,0,0,0}, aR1 = {0,0,0,0}, aZ1 = {0,0,0,0};
            #pragma unroll
            for (int kt = 0; kt < 4; kt++) {
                f16x8 a = *(const f16x8*)&h16[aoff + kt * 32];
                aR0 = __builtin_amdgcn_mfma_f32_16x16x32_f16(a, WR0[kt], aR0, 0, 0, 0);
                aZ0 = __builtin_amdgcn_mfma_f32_16x16x32_f16(a, WZ0[kt], aZ0, 0, 0, 0);
                aR1 = __builtin_amdgcn_mfma_f32_16x16x32_f16(a, WR1[kt], aR1, 0, 0, 0);
                aZ1 = __builtin_amdgcn_mfma_f32_16x16x32_f16(a, WZ1[kt], aZ1, 0, 0, 0);
            }
            float z0 = 0.0f, z1 = 0.0f;
            if (l < 16) {
                float r0 = 1.0f / (1.0f + __expf(-(aR0[0] + xr0)));
                z0       = 1.0f / (1.0f + __expf(-(aZ0[0] + xz0)));
                rh16[j0] = (_Float16)(j0 < NH ? r0 * h0 : 0.0f);
                if (has1) {
                    float r1 = 1.0f / (1.0f + __expf(-(aR1[0] + xr1)));
                    z1       = 1.0f / (1.0f + __expf(-(aZ1[0] + xz1)));
                    rh16[j1] = (_Float16)(j1 < NH ? r1 * h1 : 0.0f);
                }
            }
            bar_lgkm();                         // rh16 visible

            // ---- phase 2: Htilda = tanh(rh @ Whh + x); h update ----
            f32x4 aH0 = {0,0,0,0}, aH1 = {0,0,0,0};
            #pragma unroll
            for (int kt = 0; kt < 4; kt++) {
                f16x8 a = *(const f16x8*)&rh16[aoff + kt * 32];
                aH0 = __builtin_amdgcn_mfma_f32_16x16x32_f16(a, WH0[kt], aH0, 0, 0, 0);
                aH1 = __builtin_amdgcn_mfma_f32_16x16x32_f16(a, WH1[kt], aH1, 0, 0, 0);
            }
            if (l < 16) {
                size_t hpb = (size_t)(t * NB + b) * KP;
                {
                    float e  = __expf(2.0f * (aH0[0] + xh0));
                    float ht = 1.0f - 2.0f / (e + 1.0f);
                    float hn = fmaf(z0, ht - h0, h0);
                    hn = (j0 < NH) ? hn : 0.0f;
                    h0 = hn;
                    h16[j0] = (_Float16)hn;
                    store_hp(Hp + hpb + j0, hn);
                }
                if (has1) {
                    float e  = __expf(2.0f * (aH1[0] + xh1));
                    float ht = 1.0f - 2.0f / (e + 1.0f);
                    float hn = fmaf(z1, ht - h1, h1);
                    hn = (j1 < NH) ? hn : 0.0f;
                    h1 = hn;
                    h16[j1] = (_Float16)hn;
                    store_hp(Hp + hpb + j1, hn);
                }
            }
            bar_lgkm();                         // h16 visible for next step

            // ---- publish progress every 8 steps ----
            if ((t & 7) == 7) {
                // sc1 Hp stores retire at the LLC; vmcnt(0) drains them, then
                // a relaxed agent flag store (LLC serializes flag-after-data).
                asm volatile("s_waitcnt vmcnt(0)" ::: "memory");
                __syncthreads();
                if (tid == 0)
                    __hip_atomic_store(ctr + b, t + 1, __ATOMIC_RELAXED,
                                       __HIP_MEMORY_SCOPE_AGENT);
            }

            xr0 = pr0; xz0 = pz0; xh0 = ph0;
            xr1 = pr1; xz1 = pz1; xh1 = ph1;
        }
    } else {
        // ============ CONSUMERS: out-GEMM, n-tile-resident mapping ============
        int c  = (int)blockIdx.x - NB;       // 0..247
        int wv = tid >> 6, l = tid & 63;
        int ntl, mlo, mhi;
        if (c < NNT) { ntl = c;       mlo = 0;       mhi = (ntl < NNT - 2) ? NMT / 2 : NMT; }
        else         { ntl = c - NNT; mlo = NMT / 2; mhi = NMT; }

        int cb  = ntl * 256 + wv * 64;
        int ct0 = cb >> 5;
        const _Float16* bp = Wp + (size_t)ct0 * 7 * 512 + l * 8;
        f16x8 wb0[7], wb1[7];                // Wp slab in registers for life
        #pragma unroll
        for (int kt = 0; kt < 7; kt++) {
            wb0[kt] = *(const f16x8*)(bp + (size_t)kt * 512);
            wb1[kt] = *(const f16x8*)(bp + (size_t)(kt + 7) * 512);
        }
        int c0 = cb + (l & 31);
        float bias0 = fcb[c0], bias1 = fcb[c0 + 32];

        int done_upto = 0;
        for (int mt = mlo; mt < mhi; mt++) {
            int need = mt * 4 + 4;           // t-steps required for this m-tile
            if (need > done_upto) {
                if (tid == 0) {
                    #pragma unroll 1
                    for (int bi = 0; bi < NB; ++bi) {
                        int cur;
                        while ((cur = __hip_atomic_load(ctr + bi, __ATOMIC_RELAXED,
                                                        __HIP_MEMORY_SCOPE_AGENT)) < need) {
                            if (need - cur > 16) __builtin_amdgcn_s_sleep(64);
                            else                 __builtin_amdgcn_s_sleep(8);
                        }
                    }
                }
                __syncthreads();             // orders Hp loads after the poll
                done_upto = need;
            }

            int n0 = mt * 32;
            const _Float16* arow = Hp + (size_t)(n0 + (l & 31)) * KP + (l >> 5) * 8;
            f16x8 a[7];
            #pragma unroll
            for (int kt = 0; kt < 7; kt++)
                a[kt] = *(const f16x8*)(arow + kt * 16);

            f32x16 acc0 = {0,0,0,0,0,0,0,0,0,0,0,0,0,0,0,0};
            f32x16 acc1 = {0,0,0,0,0,0,0,0,0,0,0,0,0,0,0,0};
            #pragma unroll
            for (int kt = 0; kt < 7; kt++) {
                acc0 = __builtin_amdgcn_mfma_f32_32x32x16_f16(a[kt], wb0[kt], acc0, 0, 0, 0);
                acc1 = __builtin_amdgcn_mfma_f32_32x32x16_f16(a[kt], wb1[kt], acc1, 0, 0, 0);
            }

            #pragma unroll
            for (int p = 0; p < 16; p++) {
                int r = (p & 3) + 8 * (p >> 2) + 4 * (l >> 5);
                int m = n0 + r;
                size_t row = (size_t)(m & 7) * NT + (m >> 3);   // b*512 + t
                out[row * NV + c0]      = acc0[p] + bias0;
                out[row * NV + c0 + 32] = acc1[p] + bias1;
            }
        }
    }
}

// ---------------------------------------------------------------------------
extern "C" void kernel_launch(void* const* d_in, const int* in_sizes, int n_in,
                              void* d_out, int out_size, void* d_ws, size_t ws_size,
                              hipStream_t stream)
{
    const int*   inp = (const int*)  d_in[0];
    const float* emb = (const float*)d_in[1];
    const float* Whr = (const float*)d_in[2];
    const float* Wxr = (const float*)d_in[3];
    const float* br  = (const float*)d_in[4];
    const float* Whz = (const float*)d_in[5];
    const float* Wxz = (const float*)d_in[6];
    const float* bz  = (const float*)d_in[7];
    const float* Whh = (const float*)d_in[8];
    const float* Wxh = (const float*)d_in[9];
    const float* bh  = (const float*)d_in[10];
    const float* fcW = (const float*)d_in[11];
    const float* fcb = (const float*)d_in[12];
    float* out = (float*)d_out;

    float*    Xr = (float*)d_ws;                       // [NT*NB*NH] f32
    float*    Xz = Xr + NT * NB * NH;
    float*    Xh = Xz + NT * NB * NH;
    _Float16* Hp = (_Float16*)(Xh + NT * NB * NH);     // [NT*NB][KP] fp16
    _Float16* Wp = Hp + (size_t)NT * NB * KP;          // [1000*7*512] fp16
    _Float16* Wg = Wp + (size_t)1000 * 7 * 512;        // [84*512] fp16
    int*      ct = (int*)(Wg + (size_t)84 * 512);      // [8] progress counters

    init_kernel<<<1, 64, 0, stream>>>(ct);
    convw_kernel<<<NV / 32 / 4, 256, 0, stream>>>(fcW, Wp);
    convg_kernel<<<84, 64, 0, stream>>>(Whr, Whz, Whh, Wg);
    xproj_kernel<<<NT * NB, 128, 0, stream>>>(inp, emb, Wxr, br, Wxz, bz, Wxh, bh,
                                              Xr, Xz, Xh);
    fused_kernel<<<NBLK, 256, 0, stream>>>(Wg, Xr, Xz, Xh, Hp, Wp, fcb, out, ct);
}